// Round 5
// baseline (3406.554 us; speedup 1.0000x reference)
//
#include <hip/hip_runtime.h>
#include <hip/hip_bf16.h>
#include <hip/hip_fp16.h>
#include <cstdint>
#include <cstddef>

// ---------------- constants ----------------
#define N_ATOM 16384
#define M_NBR  12
#define NCRY   128
#define NM     (N_ATOM*M_NBR) // 196608

// output offsets (floats)
#define O_ZDEC 0
#define O_MU   44236800
#define O_LV   44237056
#define O_Z    44237312
#define O_TIF  44237568

typedef unsigned short ushort_t;
typedef float f32x4 __attribute__((ext_vector_type(4)));
typedef short bf16x8 __attribute__((ext_vector_type(8)));

__device__ __forceinline__ float sigmoidf_(float x){ return 1.f/(1.f+__expf(-x)); }
__device__ __forceinline__ float softplusf_(float x){ return fmaxf(x,0.f) + log1pf(__expf(-fabsf(x))); }
__device__ __forceinline__ uint32_t rotl32_(uint32_t x, int r){ return (x<<r)|(x>>(32-r)); }
__device__ __forceinline__ float bf2f(ushort_t u){ return __uint_as_float(((uint32_t)u)<<16); }
__device__ __forceinline__ ushort_t f2bf(float x){
  uint32_t u = __float_as_uint(x);
  uint32_t r = (u + 0x7FFFu + ((u>>16)&1u)) >> 16;
  return (ushort_t)r;
}

// ---------------- eps = jax.random.normal(key(42), (128,2)) ----------------
__global__ void gen_eps_kernel(float* __restrict__ eps){
  int j = threadIdx.x; // 256
  const uint32_t k0 = 0u, k1 = 42u;
  const uint32_t ks2 = k0 ^ k1 ^ 0x1BD11BDAu;
  uint32_t x0 = 0u + k0;
  uint32_t x1 = (uint32_t)j + k1;
#define RND_(r) { x0 += x1; x1 = rotl32_(x1, r); x1 ^= x0; }
  RND_(13) RND_(15) RND_(26) RND_(6)  x0 += k1;  x1 += ks2 + 1u;
  RND_(17) RND_(29) RND_(16) RND_(24) x0 += ks2; x1 += k0 + 2u;
  RND_(13) RND_(15) RND_(26) RND_(6)  x0 += k0;  x1 += k1 + 3u;
  RND_(17) RND_(29) RND_(16) RND_(24) x0 += k1;  x1 += ks2 + 4u;
  RND_(13) RND_(15) RND_(26) RND_(6)  x0 += ks2; x1 += k0 + 5u;
#undef RND_
  uint32_t bits = x0 ^ x1;
  float f = __uint_as_float((bits >> 9) | 0x3f800000u) - 1.0f;
  float u = __fadd_rn(__fmul_rn(f, 1.99999994f), -0.99999994f);
  u = fmaxf(-0.99999994f, u);
  float w = -log1pf(-u*u);
  float p;
  if (w < 5.0f){
    w -= 2.5f;
    p = 2.81022636e-08f;
    p = fmaf(p, w, 3.43273939e-07f);
    p = fmaf(p, w, -3.5233877e-06f);
    p = fmaf(p, w, -4.39150654e-06f);
    p = fmaf(p, w, 0.00021858087f);
    p = fmaf(p, w, -0.00125372503f);
    p = fmaf(p, w, -0.00417768164f);
    p = fmaf(p, w, 0.246640727f);
    p = fmaf(p, w, 1.50140941f);
  } else {
    w = sqrtf(w) - 3.0f;
    p = -0.000200214257f;
    p = fmaf(p, w, 0.000100950558f);
    p = fmaf(p, w, 0.00134934322f);
    p = fmaf(p, w, -0.00367342844f);
    p = fmaf(p, w, 0.00573950773f);
    p = fmaf(p, w, -0.0076224613f);
    p = fmaf(p, w, 0.00943887047f);
    p = fmaf(p, w, 1.00167406f);
    p = fmaf(p, w, 2.83297682f);
  }
  eps[j] = 1.41421356237f * (p * u);
}

// ---------------- total_input_fea output (coalesced) ------
__global__ void tif_v2(const float* __restrict__ atom, const float* __restrict__ nbr,
                       const int* __restrict__ idx, float* __restrict__ out){
  int e0 = blockIdx.x*2048 + threadIdx.x;
#pragma unroll
  for (int i=0;i<8;++i){
    int e = e0 + i*256;
    int r = e/225, c = e - r*225;
    float v;
    if (c < 92)       v = atom[(r/12)*92 + c];
    else if (c < 184) v = atom[idx[r]*92 + (c-92)];
    else              v = nbr[(size_t)r*41 + (c-184)];
    out[(size_t)e] = v;
  }
}

// ---------------- embeddings (write bf16 masters) ----------------
__global__ void embed_atom_kernel(const float* __restrict__ atom, const float* __restrict__ W,
                                  const float* __restrict__ bias, ushort_t* __restrict__ a0){
  __shared__ float row[92];
  int i = blockIdx.x; int t = threadIdx.x; // 128
  if (t < 92) row[t] = atom[i*92+t];
  __syncthreads();
  float s = bias[t];
#pragma unroll
  for (int k=0;k<92;++k) s = fmaf(row[k], W[k*128+t], s);
  a0[(size_t)i*128+t] = f2bf(s);
}

__global__ void embed_bond_kernel(const float* __restrict__ nbr, const float* __restrict__ W,
                                  const float* __restrict__ bias, ushort_t* __restrict__ nb0){
  __shared__ float rows[4][41];
  int r0 = blockIdx.x*4; int t = threadIdx.x; // 256
  if (t < 164) rows[t/41][t%41] = nbr[(size_t)r0*41 + t];
  __syncthreads();
  int rr = t >> 6, c = t & 63;
  float s = bias[c];
#pragma unroll
  for (int k=0;k<41;++k) s = fmaf(rows[rr][k], W[k*64+c], s);
  nb0[(size_t)(r0+rr)*64 + c] = f2bf(s);
}

// ---------------- idx histogram ----------------
__global__ void cnt_kernel(const int* __restrict__ idx, int* __restrict__ cnt){
  int e = blockIdx.x*256 + threadIdx.x;
  if (e < NM) atomicAdd(&cnt[idx[e]], 1);
}

// ---------------- weight transpose + bf16: Wt[o][k] = bf16(W[k][o]) ----------------
__global__ void wtr_kernel(const float* __restrict__ W, int NO, ushort_t* __restrict__ Wt){
  __shared__ ushort_t tile[32][33];
  int k0 = blockIdx.x*32, o0 = blockIdx.y*32;
  int tx = threadIdx.x & 31, ty = threadIdx.x >> 5; // 256 thr
#pragma unroll
  for (int i = ty; i < 32; i += 8)
    tile[i][tx] = f2bf(W[(size_t)(k0+i)*NO + o0 + tx]);
  __syncthreads();
#pragma unroll
  for (int i = ty; i < 32; i += 8)
    Wt[(size_t)(o0+i)*320 + k0 + tx] = tile[tx][i];
}

// ---------------- column sums for exact mean (over bf16 masters) ----------------
__global__ void colsum_a_kernel(const ushort_t* __restrict__ a, const int* __restrict__ cnt,
                                double* __restrict__ cs){
  int c = threadIdx.x; // 128
  float p1 = 0.f, p2 = 0.f;
  int i0 = blockIdx.x*128;
  for (int i=i0; i<i0+128; ++i){
    float v = bf2f(a[(size_t)i*128+c]);
    p1 += v;
    p2 += (float)cnt[i] * v;
  }
  atomicAdd(&cs[c], (double)p1);
  atomicAdd(&cs[128+c], (double)p2);
}

__global__ void colsum_nb_kernel(const ushort_t* __restrict__ nb, double* __restrict__ cs){
  __shared__ float sh[4][64];
  int t = threadIdx.x; // 256
  int c = t & 63, pr = t >> 6;
  float p = 0.f;
  size_t r0 = (size_t)blockIdx.x * 512;
  for (size_t r = r0 + pr; r < r0 + 512; r += 4) p += bf2f(nb[r*64 + c]);
  sh[pr][c] = p;
  __syncthreads();
  if (pr == 0){
    float s = sh[0][c]+sh[1][c]+sh[2][c]+sh[3][c];
    atomicAdd(&cs[256+c], (double)s);
  }
}

__global__ void mean_kernel(const double* __restrict__ cs, const ushort_t* __restrict__ Wt,
                            int NO, float* __restrict__ mean){
  int o = blockIdx.x*64 + threadIdx.x;
  if (o >= NO) return;
  const ushort_t* wr = Wt + (size_t)o*320;
  double s = 0.0;
  for (int k=0;k<128;++k)   s += 12.0*cs[k]*(double)bf2f(wr[k]);
  for (int k=128;k<320;++k) s += cs[k]*(double)bf2f(wr[k]);
  mean[o] = (float)(s / (double)NM);
}

// ---------------- MFMA conv GEMM v3 ----------------
// Block: 4 waves, 512 rows x 128 cols. Wave: 128x128 (acc 8x8 f32x4).
// B panel LDS-resident (stride 328 -> conflict-free); A dbuf, XOR chunk swizzle.
__launch_bounds__(256, 1)
__global__ void conv_gemm_v3(const ushort_t* __restrict__ a_bf, const ushort_t* __restrict__ nb_bf,
                             const int* __restrict__ idx, const ushort_t* __restrict__ Wt,
                             const float* __restrict__ mean, __half* __restrict__ O,
                             float* __restrict__ ssq){
  extern __shared__ char smem[];
  ushort_t* Bs   = (ushort_t*)smem;                        // 128*328
  ushort_t* As   = (ushort_t*)(smem + 128*328*2);          // 2*512*32
  int*      idxs = (int*)(smem + 128*328*2 + 2*512*32*2);  // 512
  float*   sqred = (float*)(smem + 128*328*2 + 2*512*32*2 + 512*4); // 128
  const int t = threadIdx.x;
  const int lane = t & 63, w = t >> 6;
  const int row0 = blockIdx.x * 512;
  const int col0 = blockIdx.y * 128;

  {
    const ushort_t* bsrc = Wt + (size_t)col0 * 320;
#pragma unroll
    for (int i = 0; i < 20; ++i){
      int e = t + i*256;
      int c = e / 40, ch = e - c*40;
      *(uint4*)&Bs[c*328 + ch*8] = *(const uint4*)(bsrc + (size_t)c*320 + ch*8);
    }
  }
  idxs[t]     = idx[row0 + t];
  idxs[t+256] = idx[row0 + 256 + t];
  if (t < 128) sqred[t] = 0.f;

  uint4 pre[8];
  auto stage_load = [&](int ks){
#pragma unroll
    for (int i=0;i<8;++i){
      int e = t + i*256;
      int r = e >> 2, ch = e & 3;
      const ushort_t* p;
      if (ks < 4)      p = a_bf + (size_t)((row0+r)/12)*128 + ks*32 + ch*8;
      else if (ks < 8) p = a_bf + (size_t)idxs[r]*128 + (ks-4)*32 + ch*8;
      else             p = nb_bf + (size_t)(row0+r)*64 + (ks-8)*32 + ch*8;
      pre[i] = *(const uint4*)p;
    }
  };
  auto stage_write = [&](int b_){
    ushort_t* dst = As + b_*(512*32);
#pragma unroll
    for (int i=0;i<8;++i){
      int e = t + i*256;
      int r = e >> 2, ch = e & 3;
      *(uint4*)&dst[r*32 + (ch ^ ((r>>2)&3))*8] = pre[i];
    }
  };

  stage_load(0); stage_write(0);
  __syncthreads();

  f32x4 acc[8][8] = {};
  const int lm = lane & 15, lg = lane >> 4;
  int buf = 0;
  for (int ks = 0; ks < 10; ++ks){
    if (ks < 9) stage_load(ks+1);
    const ushort_t* Ab = As + buf*(512*32);
    bf16x8 afr[8], bfr[8];
#pragma unroll
    for (int fn = 0; fn < 8; ++fn)
      bfr[fn] = *(const bf16x8*)&Bs[(fn*16 + lm)*328 + ks*32 + lg*8];
#pragma unroll
    for (int fm = 0; fm < 8; ++fm){
      int r = w*128 + fm*16 + lm;
      afr[fm] = *(const bf16x8*)&Ab[r*32 + ((lg ^ (lm>>2)) & 3)*8];
    }
#pragma unroll
    for (int fm = 0; fm < 8; ++fm)
#pragma unroll
      for (int fn = 0; fn < 8; ++fn)
        acc[fm][fn] = __builtin_amdgcn_mfma_f32_16x16x32_bf16(afr[fm], bfr[fn], acc[fm][fn], 0, 0, 0);
    if (ks < 9) stage_write(buf^1);
    __syncthreads();
    buf ^= 1;
  }

  float m8[8];
#pragma unroll
  for (int fn=0; fn<8; ++fn) m8[fn] = mean[col0 + fn*16 + lm];
  float sq[8] = {0.f,0.f,0.f,0.f,0.f,0.f,0.f,0.f};
#pragma unroll
  for (int fm=0; fm<8; ++fm){
#pragma unroll
    for (int fn=0; fn<8; ++fn){
#pragma unroll
      for (int j=0; j<4; ++j){
        float xc = acc[fm][fn][j] - m8[fn];
        int r = row0 + w*128 + fm*16 + lg*4 + j;
        O[(size_t)r*384 + col0 + fn*16 + lm] = __float2half(xc);
        sq[fn] += xc*xc;
      }
    }
  }
#pragma unroll
  for (int fn=0; fn<8; ++fn) atomicAdd(&sqred[fn*16 + lm], sq[fn]);
  __syncthreads();
  if (t < 128) atomicAdd(&ssq[col0 + t], sqred[t]);
}

__global__ void finalize_rs(const float* __restrict__ ssq, int C, float* __restrict__ rs){
  int c = blockIdx.x*256 + threadIdx.x;
  if (c < C) rs[c] = rsqrtf(ssq[c]/(float)NM + 1e-5f);
}

// ---------------- conv apply kernels ----
__global__ void apply_ga(const __half* __restrict__ ga, const float* __restrict__ rs,
                         const float* __restrict__ g1a, const float* __restrict__ b1a,
                         float* __restrict__ asum){
  int i = blockIdx.x; int c = threadIdx.x; // 128
  float gf  = g1a[c]     * rs[c];      float bf_ = b1a[c];
  float gc  = g1a[c+128] * rs[c+128];  float bc_ = b1a[c+128];
  float s = 0.f;
  size_t base = (size_t)i*12*384;
#pragma unroll
  for (int j=0;j<12;++j){
    float vf = __half2float(ga[base + j*384 + c]);
    float vc = __half2float(ga[base + j*384 + c + 128]);
    s += sigmoidf_(fmaf(vf, gf, bf_)) * softplusf_(fmaf(vc, gc, bc_));
  }
  asum[(size_t)i*128+c] = s;
}

__global__ void asum_stats(const float* __restrict__ asum, double* __restrict__ st){
  int c = threadIdx.x; // 128
  float s1 = 0.f, s2 = 0.f;
  int i0 = blockIdx.x*128;
  for (int i=i0;i<i0+128;++i){
    float v = asum[(size_t)i*128+c];
    s1 += v; s2 += v*v;
  }
  atomicAdd(&st[c], (double)s1);
  atomicAdd(&st[128+c], (double)s2);
}

__global__ void finalize_mr2(const double* __restrict__ st, float* __restrict__ mr2){
  int c = threadIdx.x; // 128
  double mean = st[c] / (double)N_ATOM;
  double var  = st[128+c] / (double)N_ATOM - mean*mean;
  mr2[c]     = (float)mean;
  mr2[128+c] = rsqrtf((float)var + 1e-5f);
}

__global__ void apply_out1(ushort_t* __restrict__ a0, const float* __restrict__ asum,
                           const float* __restrict__ mr2, const float* __restrict__ g2a,
                           const float* __restrict__ b2a){
  int e = blockIdx.x*256 + threadIdx.x; // n*128
  int c = e & 127;
  float g = g2a[c]*mr2[128+c];
  float b = b2a[c] - mr2[c]*g;
  a0[e] = f2bf(softplusf_(bf2f(a0[e]) + fmaf(asum[e], g, b)));
}

__global__ void apply_gb(const __half* __restrict__ gb, ushort_t* __restrict__ nb,
                         const float* __restrict__ rs, const float* __restrict__ g1b,
                         const float* __restrict__ b1b){
  int e = blockIdx.x*256 + threadIdx.x; // NM*64
  int row = e >> 6, c = e & 63;
  float vf = __half2float(gb[(size_t)row*384 + 256 + c]);
  float vc = __half2float(gb[(size_t)row*384 + 256 + c + 64]);
  float gf  = g1b[c]    * rs[256+c];     float bf_ = b1b[c];
  float gc  = g1b[c+64] * rs[256+c+64];  float bc_ = b1b[c+64];
  nb[e] = f2bf(softplusf_(bf2f(nb[e]) + sigmoidf_(fmaf(vf,gf,bf_)) * softplusf_(fmaf(vc,gc,bc_))));
}

// ---------------- pooling / VAE / decode ----------------
__global__ void pool_a_kernel(const ushort_t* __restrict__ a, float* __restrict__ pooled){
  int b = blockIdx.x; int c = threadIdx.x; // 128
  float s = 0.f;
  for (int i=0;i<128;++i) s += bf2f(a[(size_t)((b<<7)+i)*128 + c]);
  pooled[b*896 + c] = softplusf_(s * (1.f/128.f));
}

__launch_bounds__(768)
__global__ void pool_n_kernel(const ushort_t* __restrict__ nb, float* __restrict__ pooled){
  int b = blockIdx.x; int t = threadIdx.x; // 768
  float s = 0.f;
  for (int i=0;i<128;++i) s += bf2f(nb[(size_t)((b<<7)+i)*768 + t]);
  pooled[b*896 + 128 + t] = softplusf_(s * (1.f/128.f));
}

__global__ void muz_kernel(const float* __restrict__ pooled, const float* __restrict__ muW,
                           const float* __restrict__ mub, const float* __restrict__ lvW,
                           const float* __restrict__ lvb, const float* __restrict__ eps,
                           float* __restrict__ out_mu, float* __restrict__ out_lv,
                           float* __restrict__ out_z, float* __restrict__ zws){
  int t = threadIdx.x; // 256 -> (b,l)
  int b = t >> 1, l = t & 1;
  const float* pr = pooled + b*896;
  float smu = mub[l], slv = lvb[l];
  for (int k=0;k<896;++k){
    float p = pr[k];
    smu = fmaf(p, muW[k*2+l], smu);
    slv = fmaf(p, lvW[k*2+l], slv);
  }
  out_mu[t] = smu; out_lv[t] = slv;
  float zv = fmaf(eps[t], __expf(0.5f*slv), smu);
  out_z[t] = zv; zws[t] = zv;
}

__global__ void compute_f_kernel(const float* __restrict__ zws, const float* __restrict__ decW,
                                 const float* __restrict__ decb, const float* __restrict__ pooled,
                                 float* __restrict__ f){
  int b = blockIdx.x;
  float z0 = zws[b*2], z1 = zws[b*2+1];
  for (int k = threadIdx.x; k < 896; k += 256){
    float zd = fmaf(z0, decW[k], fmaf(z1, decW[896+k], decb[k]));
    f[b*896+k] = zd / pooled[b*896+k];
  }
}

__global__ void dec_atom_kernel(ushort_t* __restrict__ a, const float* __restrict__ f){
  int e = blockIdx.x*256+threadIdx.x; // n*128
  int c = e & 127; int b = e >> 14;
  a[e] = f2bf(softplusf_(bf2f(a[e]) * f[b*896 + c]));
}

__global__ void dec_bond_kernel(ushort_t* __restrict__ nb, const float* __restrict__ f){
  int i = blockIdx.x; int off = blockIdx.y*256 + threadIdx.x; // off < 768
  int b = i >> 7;
  size_t e = (size_t)i*768 + off;
  nb[e] = f2bf(softplusf_(bf2f(nb[e]) * f[b*896 + 128 + off]));
}

// ---------------- final embeddings ----------------
__global__ void embed_atom2_kernel(const ushort_t* __restrict__ a, const float* __restrict__ W,
                                   const float* __restrict__ bias, float* __restrict__ za2){
  __shared__ float row[128];
  int i = blockIdx.x; int t = threadIdx.x; // 128
  row[t] = bf2f(a[(size_t)i*128+t]);
  __syncthreads();
  if (t < 92){
    float s = bias[t];
#pragma unroll
    for (int k=0;k<128;++k) s = fmaf(row[k], W[k*92+t], s);
    za2[(size_t)i*92+t] = sigmoidf_(s);
  }
}

__global__ void bproj_kernel(const ushort_t* __restrict__ nb, const float* __restrict__ W,
                             const float* __restrict__ bias, float* __restrict__ bp){
  __shared__ float Ws[64][41];
  __shared__ float rows[6][64];
  int t = threadIdx.x; // 256
  for (int e=t; e<64*41; e+=256) Ws[e/41][e%41] = W[e];
  int r0 = blockIdx.x*6;
  for (int e=t; e<6*64; e+=256){
    int rr = e>>6, c = e&63;
    rows[rr][c] = bf2f(nb[(size_t)(r0+rr)*64 + c]);
  }
  __syncthreads();
  if (t < 246){
    int rr = t/41, o = t - rr*41;
    float s = bias[o];
#pragma unroll
    for (int k=0;k<64;++k) s = fmaf(rows[rr][k], Ws[k][o], s);
    bp[(size_t)(r0+rr)*41 + o] = sigmoidf_(s);
  }
}

__global__ void zdec_v2(const float* __restrict__ za2, const float* __restrict__ bp,
                        const int* __restrict__ idx, float* __restrict__ out){
  int e0 = blockIdx.x*2048 + threadIdx.x;
#pragma unroll
  for (int i=0;i<8;++i){
    int e = e0 + i*256;
    int r = e/225, c = e - r*225;
    float v;
    if (c < 92)       v = za2[(size_t)(r/12)*92 + c];
    else if (c < 184) v = za2[(size_t)idx[r]*92 + (c-92)];
    else              v = bp[(size_t)r*41 + (c-184)];
    out[(size_t)e] = v;
  }
}

// ---------------- host side ----------------
#define GEMM_LDS 152064

struct WsPlan {
  ushort_t *Abf, *NBbf, *Wt;
  __half* big;
  float *asum, *pooled, *fbuf, *zws, *eps, *mean, *rs, *mr2, *ssq;
  int* cnt;
  double *cs, *st;
};

static void conv_pass(const WsPlan& P, const int* idx,
                      const float* Wa, const float* Wb,
                      const float* g1a, const float* b1a, const float* g1b, const float* b1b,
                      const float* g2a, const float* b2a,
                      hipStream_t stream){
  wtr_kernel<<<dim3(10,8), 256, 0, stream>>>(Wa, 256, P.Wt);
  wtr_kernel<<<dim3(10,4), 256, 0, stream>>>(Wb, 128, P.Wt + 256*320);
  hipMemsetAsync(P.cs, 0, 320*8 + 256*8 + 384*4, stream);
  colsum_a_kernel<<<128, 128, 0, stream>>>(P.Abf, P.cnt, P.cs);
  colsum_nb_kernel<<<NM/512, 256, 0, stream>>>(P.NBbf, P.cs);
  mean_kernel<<<6, 64, 0, stream>>>(P.cs, P.Wt, 384, P.mean);
  conv_gemm_v3<<<dim3(NM/512, 3), 256, GEMM_LDS, stream>>>(P.Abf, P.NBbf, idx, P.Wt, P.mean, P.big, P.ssq);
  finalize_rs<<<2, 256, 0, stream>>>(P.ssq, 384, P.rs);
  apply_ga<<<N_ATOM, 128, 0, stream>>>(P.big, P.rs, g1a, b1a, P.asum);
  asum_stats<<<128, 128, 0, stream>>>(P.asum, P.st);
  finalize_mr2<<<1, 128, 0, stream>>>(P.st, P.mr2);
  apply_out1<<<N_ATOM*128/256, 256, 0, stream>>>(P.Abf, P.asum, P.mr2, g2a, b2a);
  apply_gb<<<NM*64/256, 256, 0, stream>>>(P.big, P.NBbf, P.rs, g1b, b1b);
}

extern "C" void kernel_launch(void* const* d_in, const int* in_sizes, int n_in,
                              void* d_out, int out_size, void* d_ws, size_t ws_size,
                              hipStream_t stream) {
  (void)in_sizes; (void)n_in; (void)out_size; (void)ws_size;
  const float* atom_fea   = (const float*)d_in[0];
  const float* nbr_fea    = (const float*)d_in[1];
  const int*   idx        = (const int*)d_in[2];
  const float* emb_atom_W = (const float*)d_in[4];
  const float* emb_atom_b = (const float*)d_in[5];
  const float* emb_bond_W = (const float*)d_in[6];
  const float* emb_bond_b = (const float*)d_in[7];
  const float* emb_atom2_W= (const float*)d_in[8];
  const float* emb_atom2_b= (const float*)d_in[9];
  const float* emb_bond2_W= (const float*)d_in[10];
  const float* emb_bond2_b= (const float*)d_in[11];
  const float* mu_W       = (const float*)d_in[12];
  const float* mu_b       = (const float*)d_in[13];
  const float* lv_W       = (const float*)d_in[14];
  const float* lv_b       = (const float*)d_in[15];
  const float* dec_W      = (const float*)d_in[16];
  const float* dec_b      = (const float*)d_in[17];
  const float* c1_Wa  = (const float*)d_in[18];
  const float* c1_Wb  = (const float*)d_in[19];
  const float* c1_g1a = (const float*)d_in[20];
  const float* c1_b1a = (const float*)d_in[21];
  const float* c1_g1b = (const float*)d_in[22];
  const float* c1_b1b = (const float*)d_in[23];
  const float* c1_g2a = (const float*)d_in[24];
  const float* c1_b2a = (const float*)d_in[25];
  const float* c2_Wa  = (const float*)d_in[26];
  const float* c2_Wb  = (const float*)d_in[27];
  const float* c2_g1a = (const float*)d_in[28];
  const float* c2_b1a = (const float*)d_in[29];
  const float* c2_g1b = (const float*)d_in[30];
  const float* c2_b1b = (const float*)d_in[31];
  const float* c2_g2a = (const float*)d_in[32];
  const float* c2_b2a = (const float*)d_in[33];

  float* out = (float*)d_out;

  hipFuncSetAttribute((const void*)conv_gemm_v3,
                      hipFuncAttributeMaxDynamicSharedMemorySize, GEMM_LDS);

  WsPlan P;
  char* w = (char*)d_ws;
  auto alloc = [&](size_t bytes) -> char* {
    char* p = w; w += (bytes + 255) & ~(size_t)255; return p;
  };
  P.Abf    = (ushort_t*)alloc((size_t)N_ATOM*128*2);
  P.NBbf   = (ushort_t*)alloc((size_t)NM*64*2);
  P.big    = (__half*)  alloc((size_t)NM*384*2);
  P.asum   = (float*)   alloc((size_t)N_ATOM*128*4);
  P.pooled = (float*)   alloc(114688*4);
  P.fbuf   = (float*)   alloc(114688*4);
  P.Wt     = (ushort_t*)alloc(384*320*2);
  P.zws    = (float*)   alloc(256*4);
  P.eps    = (float*)   alloc(256*4);
  P.mean   = (float*)   alloc(384*4);
  P.rs     = (float*)   alloc(384*4);
  P.mr2    = (float*)   alloc(256*4);
  P.cnt    = (int*)     alloc(N_ATOM*4);
  P.cs     = (double*)  alloc(320*8);
  P.st     = (double*)  alloc(256*8);
  P.ssq    = (float*)   alloc(384*4);
  float* za2   = P.asum;
  float* bproj = (float*)P.big;

  gen_eps_kernel<<<1, 256, 0, stream>>>(P.eps);
  tif_v2<<<21600, 256, 0, stream>>>(atom_fea, nbr_fea, idx, out + O_TIF);
  embed_atom_kernel<<<N_ATOM, 128, 0, stream>>>(atom_fea, emb_atom_W, emb_atom_b, P.Abf);
  embed_bond_kernel<<<NM/4, 256, 0, stream>>>(nbr_fea, emb_bond_W, emb_bond_b, P.NBbf);
  hipMemsetAsync(P.cnt, 0, N_ATOM*sizeof(int), stream);
  cnt_kernel<<<NM/256, 256, 0, stream>>>(idx, P.cnt);

  for (int L=0; L<3; ++L){
    conv_pass(P, idx, c1_Wa + (size_t)L*320*256, c1_Wb + (size_t)L*320*128,
              c1_g1a+L*256, c1_b1a+L*256, c1_g1b+L*128, c1_b1b+L*128,
              c1_g2a+L*128, c1_b2a+L*128, stream);
  }

  pool_a_kernel<<<NCRY, 128, 0, stream>>>(P.Abf, P.pooled);
  pool_n_kernel<<<NCRY, 768, 0, stream>>>(P.NBbf, P.pooled);
  muz_kernel<<<1, 256, 0, stream>>>(P.pooled, mu_W, mu_b, lv_W, lv_b, P.eps,
                                    out + O_MU, out + O_LV, out + O_Z, P.zws);
  compute_f_kernel<<<NCRY, 256, 0, stream>>>(P.zws, dec_W, dec_b, P.pooled, P.fbuf);
  dec_atom_kernel<<<N_ATOM*128/256, 256, 0, stream>>>(P.Abf, P.fbuf);
  dim3 gdb(N_ATOM, 3);
  dec_bond_kernel<<<gdb, 256, 0, stream>>>(P.NBbf, P.fbuf);

  for (int L=0; L<3; ++L){
    conv_pass(P, idx, c2_Wa + (size_t)L*320*256, c2_Wb + (size_t)L*320*128,
              c2_g1a+L*256, c2_b1a+L*256, c2_g1b+L*128, c2_b1b+L*128,
              c2_g2a+L*128, c2_b2a+L*128, stream);
  }

  embed_atom2_kernel<<<N_ATOM, 128, 0, stream>>>(P.Abf, emb_atom2_W, emb_atom2_b, za2);
  bproj_kernel<<<NM/6, 256, 0, stream>>>(P.NBbf, emb_bond2_W, emb_bond2_b, bproj);
  zdec_v2<<<21600, 256, 0, stream>>>(za2, bproj, idx, out + O_ZDEC);
}

// Round 6
// 3315.642 us; speedup vs baseline: 1.0274x; 1.0274x over previous
//
#include <hip/hip_runtime.h>
#include <hip/hip_bf16.h>
#include <hip/hip_fp16.h>
#include <cstdint>
#include <cstddef>

// ---------------- constants ----------------
#define N_ATOM 16384
#define M_NBR  12
#define NCRY   128
#define NM     (N_ATOM*M_NBR) // 196608

// output offsets (floats)
#define O_ZDEC 0
#define O_MU   44236800
#define O_LV   44237056
#define O_Z    44237312
#define O_TIF  44237568

typedef unsigned short ushort_t;
typedef float f32x4 __attribute__((ext_vector_type(4)));
typedef short bf16x8 __attribute__((ext_vector_type(8)));

__device__ __forceinline__ float sigmoidf_(float x){ return 1.f/(1.f+__expf(-x)); }
__device__ __forceinline__ float softplusf_(float x){ return fmaxf(x,0.f) + log1pf(__expf(-fabsf(x))); }
__device__ __forceinline__ uint32_t rotl32_(uint32_t x, int r){ return (x<<r)|(x>>(32-r)); }
__device__ __forceinline__ float bf2f(ushort_t u){ return __uint_as_float(((uint32_t)u)<<16); }
__device__ __forceinline__ ushort_t f2bf(float x){
  uint32_t u = __float_as_uint(x);
  uint32_t r = (u + 0x7FFFu + ((u>>16)&1u)) >> 16;
  return (ushort_t)r;
}

// ---------------- eps = jax.random.normal(key(42), (128,2)) ----------------
__global__ void gen_eps_kernel(float* __restrict__ eps){
  int j = threadIdx.x; // 256
  const uint32_t k0 = 0u, k1 = 42u;
  const uint32_t ks2 = k0 ^ k1 ^ 0x1BD11BDAu;
  uint32_t x0 = 0u + k0;
  uint32_t x1 = (uint32_t)j + k1;
#define RND_(r) { x0 += x1; x1 = rotl32_(x1, r); x1 ^= x0; }
  RND_(13) RND_(15) RND_(26) RND_(6)  x0 += k1;  x1 += ks2 + 1u;
  RND_(17) RND_(29) RND_(16) RND_(24) x0 += ks2; x1 += k0 + 2u;
  RND_(13) RND_(15) RND_(26) RND_(6)  x0 += k0;  x1 += k1 + 3u;
  RND_(17) RND_(29) RND_(16) RND_(24) x0 += k1;  x1 += ks2 + 4u;
  RND_(13) RND_(15) RND_(26) RND_(6)  x0 += ks2; x1 += k0 + 5u;
#undef RND_
  uint32_t bits = x0 ^ x1;
  float f = __uint_as_float((bits >> 9) | 0x3f800000u) - 1.0f;
  float u = __fadd_rn(__fmul_rn(f, 1.99999994f), -0.99999994f);
  u = fmaxf(-0.99999994f, u);
  float w = -log1pf(-u*u);
  float p;
  if (w < 5.0f){
    w -= 2.5f;
    p = 2.81022636e-08f;
    p = fmaf(p, w, 3.43273939e-07f);
    p = fmaf(p, w, -3.5233877e-06f);
    p = fmaf(p, w, -4.39150654e-06f);
    p = fmaf(p, w, 0.00021858087f);
    p = fmaf(p, w, -0.00125372503f);
    p = fmaf(p, w, -0.00417768164f);
    p = fmaf(p, w, 0.246640727f);
    p = fmaf(p, w, 1.50140941f);
  } else {
    w = sqrtf(w) - 3.0f;
    p = -0.000200214257f;
    p = fmaf(p, w, 0.000100950558f);
    p = fmaf(p, w, 0.00134934322f);
    p = fmaf(p, w, -0.00367342844f);
    p = fmaf(p, w, 0.00573950773f);
    p = fmaf(p, w, -0.0076224613f);
    p = fmaf(p, w, 0.00943887047f);
    p = fmaf(p, w, 1.00167406f);
    p = fmaf(p, w, 2.83297682f);
  }
  eps[j] = 1.41421356237f * (p * u);
}

// ---------------- total_input_fea output (coalesced) ------
__global__ void tif_v2(const float* __restrict__ atom, const float* __restrict__ nbr,
                       const int* __restrict__ idx, float* __restrict__ out){
  int e0 = blockIdx.x*2048 + threadIdx.x;
#pragma unroll
  for (int i=0;i<8;++i){
    int e = e0 + i*256;
    int r = e/225, c = e - r*225;
    float v;
    if (c < 92)       v = atom[(r/12)*92 + c];
    else if (c < 184) v = atom[idx[r]*92 + (c-92)];
    else              v = nbr[(size_t)r*41 + (c-184)];
    out[(size_t)e] = v;
  }
}

// ---------------- embeddings (write bf16 masters) ----------------
__global__ void embed_atom_kernel(const float* __restrict__ atom, const float* __restrict__ W,
                                  const float* __restrict__ bias, ushort_t* __restrict__ a0){
  __shared__ float row[92];
  int i = blockIdx.x; int t = threadIdx.x; // 128
  if (t < 92) row[t] = atom[i*92+t];
  __syncthreads();
  float s = bias[t];
#pragma unroll
  for (int k=0;k<92;++k) s = fmaf(row[k], W[k*128+t], s);
  a0[(size_t)i*128+t] = f2bf(s);
}

__global__ void embed_bond_kernel(const float* __restrict__ nbr, const float* __restrict__ W,
                                  const float* __restrict__ bias, ushort_t* __restrict__ nb0){
  __shared__ float rows[4][41];
  int r0 = blockIdx.x*4; int t = threadIdx.x; // 256
  if (t < 164) rows[t/41][t%41] = nbr[(size_t)r0*41 + t];
  __syncthreads();
  int rr = t >> 6, c = t & 63;
  float s = bias[c];
#pragma unroll
  for (int k=0;k<41;++k) s = fmaf(rows[rr][k], W[k*64+c], s);
  nb0[(size_t)(r0+rr)*64 + c] = f2bf(s);
}

// ---------------- idx histogram ----------------
__global__ void cnt_kernel(const int* __restrict__ idx, int* __restrict__ cnt){
  int e = blockIdx.x*256 + threadIdx.x;
  if (e < NM) atomicAdd(&cnt[idx[e]], 1);
}

// ---------------- weight transpose (Wa+Wb fused): Wt[o][k] = bf16(W[k][o]) ----------
__global__ void wtr2_kernel(const float* __restrict__ Wa, const float* __restrict__ Wb,
                            ushort_t* __restrict__ Wt){
  __shared__ ushort_t tile[32][33];
  int by = blockIdx.y;
  const float* W; int NO, o0, obase;
  if (by < 8){ W = Wa; NO = 256; o0 = by*32; obase = o0; }
  else       { W = Wb; NO = 128; o0 = (by-8)*32; obase = 256 + o0; }
  int k0 = blockIdx.x*32;
  int tx = threadIdx.x & 31, ty = threadIdx.x >> 5; // 256 thr
#pragma unroll
  for (int i = ty; i < 32; i += 8)
    tile[i][tx] = f2bf(W[(size_t)(k0+i)*NO + o0 + tx]);
  __syncthreads();
#pragma unroll
  for (int i = ty; i < 32; i += 8)
    Wt[(size_t)(obase+i)*320 + k0 + tx] = tile[tx][i];
}

// ---------------- fused column sums for exact mean ----------------
// cs[0..127] self-sum, cs[128..255] cnt-weighted sum, cs[256..319] nb sum
__global__ void colsum_all(const ushort_t* __restrict__ a, const ushort_t* __restrict__ nb,
                           const int* __restrict__ cnt, double* __restrict__ cs){
  int bx = blockIdx.x; int t = threadIdx.x; // 256
  if (bx < 128){
    int c = t & 127, h = t >> 7;
    float p1 = 0.f, p2 = 0.f;
    int i0 = bx*128;
    for (int i=i0+h; i<i0+128; i+=2){
      float v = bf2f(a[(size_t)i*128+c]);
      p1 += v;
      p2 += (float)cnt[i] * v;
    }
    atomicAdd(&cs[c], (double)p1);
    atomicAdd(&cs[128+c], (double)p2);
  } else {
    __shared__ float sh[4][64];
    int c = t & 63, pr = t >> 6;
    float p = 0.f;
    size_t r0 = (size_t)(bx-128) * 512;
    for (size_t r = r0 + pr; r < r0 + 512; r += 4) p += bf2f(nb[r*64 + c]);
    sh[pr][c] = p;
    __syncthreads();
    if (pr == 0){
      float s = sh[0][c]+sh[1][c]+sh[2][c]+sh[3][c];
      atomicAdd(&cs[256+c], (double)s);
    }
  }
}

__global__ void mean_kernel(const double* __restrict__ cs, const ushort_t* __restrict__ Wt,
                            int NO, float* __restrict__ mean){
  int o = blockIdx.x*64 + threadIdx.x;
  if (o >= NO) return;
  const ushort_t* wr = Wt + (size_t)o*320;
  double s = 0.0;
  for (int k=0;k<128;++k)   s += 12.0*cs[k]*(double)bf2f(wr[k]);
  for (int k=128;k<320;++k) s += cs[k]*(double)bf2f(wr[k]);
  mean[o] = (float)(s / (double)NM);
}

// ---------------- MFMA conv GEMM v4 (m97 geometry) ----------------
// Block 128 rows x 128 cols, 4 waves (2x2), wave 64x64: acc 4x4 f32x4 = 64 VGPR.
// BK=32 double-buffered [128][32] linear LDS; MFMA:ds_read = 2:1; 3 waves/SIMD.
// Epilogue: centered f16 staged via LDS [128][136] -> coalesced dwordx4 stores + fused ssq.
__launch_bounds__(256, 3)
__global__ void conv_gemm_v4(const ushort_t* __restrict__ a_bf, const ushort_t* __restrict__ nb_bf,
                             const int* __restrict__ idx, const ushort_t* __restrict__ Wt,
                             const float* __restrict__ mean, __half* __restrict__ O,
                             float* __restrict__ ssq){
  __shared__ ushort_t sm[17408];          // staging: As 2x4096 @0, Bs 2x4096 @8192; epilogue [128][136]
  __shared__ float sqred[128];
  ushort_t* As0 = sm;        ushort_t* As1 = sm + 4096;
  ushort_t* Bs0 = sm + 8192; ushort_t* Bs1 = sm + 12288;
  const int t = threadIdx.x;
  const int lane = t & 63;
  const int w = t >> 6, wr = w >> 1, wc = w & 1;
  const int lm = lane & 15, lg = lane >> 4;
  const int row0 = blockIdx.x * 128, col0 = blockIdx.y * 128;

  const int rr0 = t >> 2, ch = t & 3;     // staging: rows rr0, rr0+64; 16B chunk ch
  int idxr0 = idx[row0 + rr0];
  int idxr1 = idx[row0 + 64 + rr0];

  uint4 pa[2], pb[2];
  auto stage_load = [&](int ks){
#pragma unroll
    for (int i=0;i<2;++i){
      int rr = rr0 + i*64;
      const ushort_t* p;
      if (ks < 4)      p = a_bf + (size_t)((row0+rr)/12)*128 + ks*32 + ch*8;
      else if (ks < 8) p = a_bf + (size_t)(i ? idxr1 : idxr0)*128 + (ks-4)*32 + ch*8;
      else             p = nb_bf + (size_t)(row0+rr)*64 + (ks-8)*32 + ch*8;
      pa[i] = *(const uint4*)p;
      pb[i] = *(const uint4*)(Wt + (size_t)(col0+rr)*320 + ks*32 + ch*8);
    }
  };
  auto stage_write = [&](ushort_t* Ad, ushort_t* Bd){
#pragma unroll
    for (int i=0;i<2;++i){
      *(uint4*)&Ad[(t + i*256)*8] = pa[i];
      *(uint4*)&Bd[(t + i*256)*8] = pb[i];
    }
  };

  stage_load(0); stage_write(As0, Bs0);
  __syncthreads();

  f32x4 acc[4][4] = {};
  int buf = 0;
#pragma unroll
  for (int ks = 0; ks < 10; ++ks){
    if (ks < 9) stage_load(ks+1);
    const ushort_t* Ab = buf ? As1 : As0;
    const ushort_t* Bb = buf ? Bs1 : Bs0;
    bf16x8 afr[4], bfr[4];
#pragma unroll
    for (int fm=0; fm<4; ++fm)
      afr[fm] = *(const bf16x8*)&Ab[(wr*64 + fm*16 + lm)*32 + lg*8];
#pragma unroll
    for (int fn=0; fn<4; ++fn)
      bfr[fn] = *(const bf16x8*)&Bb[(wc*64 + fn*16 + lm)*32 + lg*8];
#pragma unroll
    for (int fm=0; fm<4; ++fm)
#pragma unroll
      for (int fn=0; fn<4; ++fn)
        acc[fm][fn] = __builtin_amdgcn_mfma_f32_16x16x32_bf16(afr[fm], bfr[fn], acc[fm][fn], 0, 0, 0);
    if (ks < 9) stage_write(buf ? As0 : As1, buf ? Bs0 : Bs1);
    __syncthreads();
    buf ^= 1;
  }
  // after final barrier all LDS reads are done; reuse sm as the output tile [128][136] f16

  float m4[4];
#pragma unroll
  for (int fn=0; fn<4; ++fn) m4[fn] = mean[col0 + wc*64 + fn*16 + lm];
  if (t < 128) sqred[t] = 0.f;

#pragma unroll
  for (int fm=0; fm<4; ++fm){
    int rw = wr*64 + fm*16 + lg*4;
#pragma unroll
    for (int fn=0; fn<4; ++fn){
      int cl = wc*64 + fn*16 + lm;
#pragma unroll
      for (int j=0; j<4; ++j){
        float xc = acc[fm][fn][j] - m4[fn];
        __half h = __float2half(xc);
        sm[(rw+j)*136 + cl] = *(ushort_t*)&h;
      }
    }
  }
  __syncthreads();

  const int cch = t & 15, rb = t >> 4;
  float sq[8] = {0.f,0.f,0.f,0.f,0.f,0.f,0.f,0.f};
#pragma unroll
  for (int i=0; i<8; ++i){
    int row = rb + i*16;
    uint4 v = *(const uint4*)&sm[row*136 + cch*8];
    *(uint4*)(O + (size_t)(row0+row)*384 + col0 + cch*8) = v;
    const __half* hp = (const __half*)&v;
#pragma unroll
    for (int k=0;k<8;++k){
      float f = __half2float(hp[k]);
      sq[k] += f*f;
    }
  }
#pragma unroll
  for (int k=0;k<8;++k) atomicAdd(&sqred[cch*8+k], sq[k]);
  __syncthreads();
  if (t < 128) atomicAdd(&ssq[col0 + t], sqred[t]);
}

// ---------------- conv apply kernels (x centered: BN = x*rs*g + b; rs inline) ----
__global__ void apply_ga(const __half* __restrict__ ga, const float* __restrict__ ssq,
                         const float* __restrict__ g1a, const float* __restrict__ b1a,
                         float* __restrict__ asum){
  int t = threadIdx.x; // 256
  int c = t & 127;
  int i = blockIdx.x*2 + (t>>7);
  float rf = rsqrtf(ssq[c]*(1.f/NM) + 1e-5f);
  float rc = rsqrtf(ssq[c+128]*(1.f/NM) + 1e-5f);
  float gf  = g1a[c]     * rf;   float bf_ = b1a[c];
  float gc  = g1a[c+128] * rc;   float bc_ = b1a[c+128];
  float s = 0.f;
  size_t base = (size_t)i*12*384;
#pragma unroll
  for (int j=0;j<12;++j){
    float vf = __half2float(ga[base + j*384 + c]);
    float vc = __half2float(ga[base + j*384 + c + 128]);
    s += sigmoidf_(fmaf(vf, gf, bf_)) * softplusf_(fmaf(vc, gc, bc_));
  }
  asum[(size_t)i*128+c] = s;
}

__global__ void asum_stats(const float* __restrict__ asum, double* __restrict__ st){
  int t = threadIdx.x; // 256
  int c = t & 127, h = t >> 7;
  float s1 = 0.f, s2 = 0.f;
  int i0 = blockIdx.x*256;
  for (int i=i0+h;i<i0+256;i+=2){
    float v = asum[(size_t)i*128+c];
    s1 += v; s2 += v*v;
  }
  atomicAdd(&st[c], (double)s1);
  atomicAdd(&st[128+c], (double)s2);
}

__global__ void finalize_mr2(const double* __restrict__ st, float* __restrict__ mr2){
  int c = threadIdx.x; // 128
  double mean = st[c] / (double)N_ATOM;
  double var  = st[128+c] / (double)N_ATOM - mean*mean;
  mr2[c]     = (float)mean;
  mr2[128+c] = rsqrtf((float)var + 1e-5f);
}

__global__ void apply_out1(ushort_t* __restrict__ a0, const float* __restrict__ asum,
                           const float* __restrict__ mr2, const float* __restrict__ g2a,
                           const float* __restrict__ b2a){
  int e = blockIdx.x*256 + threadIdx.x; // n*128
  int c = e & 127;
  float g = g2a[c]*mr2[128+c];
  float b = b2a[c] - mr2[c]*g;
  a0[e] = f2bf(softplusf_(bf2f(a0[e]) + fmaf(asum[e], g, b)));
}

__global__ void apply_gb(const __half* __restrict__ gb, ushort_t* __restrict__ nb,
                         const float* __restrict__ ssq, const float* __restrict__ g1b,
                         const float* __restrict__ b1b){
  int e = blockIdx.x*256 + threadIdx.x; // NM*64
  int row = e >> 6, c = e & 63;
  float vf = __half2float(gb[(size_t)row*384 + 256 + c]);
  float vc = __half2float(gb[(size_t)row*384 + 256 + c + 64]);
  float rf = rsqrtf(ssq[256+c]*(1.f/NM) + 1e-5f);
  float rc = rsqrtf(ssq[256+c+64]*(1.f/NM) + 1e-5f);
  float gf  = g1b[c]    * rf;   float bf_ = b1b[c];
  float gc  = g1b[c+64] * rc;   float bc_ = b1b[c+64];
  nb[e] = f2bf(softplusf_(bf2f(nb[e]) + sigmoidf_(fmaf(vf,gf,bf_)) * softplusf_(fmaf(vc,gc,bc_))));
}

// ---------------- pooling / VAE / decode ----------------
__global__ void pool_a_kernel(const ushort_t* __restrict__ a, float* __restrict__ pooled){
  int b = blockIdx.x; int c = threadIdx.x; // 128
  float s = 0.f;
  for (int i=0;i<128;++i) s += bf2f(a[(size_t)((b<<7)+i)*128 + c]);
  pooled[b*896 + c] = softplusf_(s * (1.f/128.f));
}

__launch_bounds__(768)
__global__ void pool_n_kernel(const ushort_t* __restrict__ nb, float* __restrict__ pooled){
  int b = blockIdx.x; int t = threadIdx.x; // 768
  float s = 0.f;
  for (int i=0;i<128;++i) s += bf2f(nb[(size_t)((b<<7)+i)*768 + t]);
  pooled[b*896 + 128 + t] = softplusf_(s * (1.f/128.f));
}

__global__ void muz_kernel(const float* __restrict__ pooled, const float* __restrict__ muW,
                           const float* __restrict__ mub, const float* __restrict__ lvW,
                           const float* __restrict__ lvb, const float* __restrict__ eps,
                           float* __restrict__ out_mu, float* __restrict__ out_lv,
                           float* __restrict__ out_z, float* __restrict__ zws){
  int t = threadIdx.x; // 256 -> (b,l)
  int b = t >> 1, l = t & 1;
  const float* pr = pooled + b*896;
  float smu = mub[l], slv = lvb[l];
  for (int k=0;k<896;++k){
    float p = pr[k];
    smu = fmaf(p, muW[k*2+l], smu);
    slv = fmaf(p, lvW[k*2+l], slv);
  }
  out_mu[t] = smu; out_lv[t] = slv;
  float zv = fmaf(eps[t], __expf(0.5f*slv), smu);
  out_z[t] = zv; zws[t] = zv;
}

__global__ void compute_f_kernel(const float* __restrict__ zws, const float* __restrict__ decW,
                                 const float* __restrict__ decb, const float* __restrict__ pooled,
                                 float* __restrict__ f){
  int b = blockIdx.x;
  float z0 = zws[b*2], z1 = zws[b*2+1];
  for (int k = threadIdx.x; k < 896; k += 256){
    float zd = fmaf(z0, decW[k], fmaf(z1, decW[896+k], decb[k]));
    f[b*896+k] = zd / pooled[b*896+k];
  }
}

__global__ void dec_atom_kernel(ushort_t* __restrict__ a, const float* __restrict__ f){
  int e = blockIdx.x*256+threadIdx.x; // n*128
  int c = e & 127; int b = e >> 14;
  a[e] = f2bf(softplusf_(bf2f(a[e]) * f[b*896 + c]));
}

__global__ void dec_bond_kernel(ushort_t* __restrict__ nb, const float* __restrict__ f){
  int i = blockIdx.x; int off = blockIdx.y*256 + threadIdx.x; // off < 768
  int b = i >> 7;
  size_t e = (size_t)i*768 + off;
  nb[e] = f2bf(softplusf_(bf2f(nb[e]) * f[b*896 + 128 + off]));
}

// ---------------- final embeddings ----------------
__global__ void embed_atom2_kernel(const ushort_t* __restrict__ a, const float* __restrict__ W,
                                   const float* __restrict__ bias, float* __restrict__ za2){
  __shared__ float row[128];
  int i = blockIdx.x; int t = threadIdx.x; // 128
  row[t] = bf2f(a[(size_t)i*128+t]);
  __syncthreads();
  if (t < 92){
    float s = bias[t];
#pragma unroll
    for (int k=0;k<128;++k) s = fmaf(row[k], W[k*92+t], s);
    za2[(size_t)i*92+t] = sigmoidf_(s);
  }
}

__global__ void bproj_kernel(const ushort_t* __restrict__ nb, const float* __restrict__ W,
                             const float* __restrict__ bias, float* __restrict__ bp){
  __shared__ float Ws[64][41];
  __shared__ float rows[6][64];
  int t = threadIdx.x; // 256
  for (int e=t; e<64*41; e+=256) Ws[e/41][e%41] = W[e];
  int r0 = blockIdx.x*6;
  for (int e=t; e<6*64; e+=256){
    int rr = e>>6, c = e&63;
    rows[rr][c] = bf2f(nb[(size_t)(r0+rr)*64 + c]);
  }
  __syncthreads();
  if (t < 246){
    int rr = t/41, o = t - rr*41;
    float s = bias[o];
#pragma unroll
    for (int k=0;k<64;++k) s = fmaf(rows[rr][k], Ws[k][o], s);
    bp[(size_t)(r0+rr)*41 + o] = sigmoidf_(s);
  }
}

__global__ void zdec_v2(const float* __restrict__ za2, const float* __restrict__ bp,
                        const int* __restrict__ idx, float* __restrict__ out){
  int e0 = blockIdx.x*2048 + threadIdx.x;
#pragma unroll
  for (int i=0;i<8;++i){
    int e = e0 + i*256;
    int r = e/225, c = e - r*225;
    float v;
    if (c < 92)       v = za2[(size_t)(r/12)*92 + c];
    else if (c < 184) v = za2[(size_t)idx[r]*92 + (c-92)];
    else              v = bp[(size_t)r*41 + (c-184)];
    out[(size_t)e] = v;
  }
}

// ---------------- host side ----------------
struct WsPlan {
  ushort_t *Abf, *NBbf, *Wt;
  __half* big;
  float *asum, *pooled, *fbuf, *zws, *eps, *mean, *mr2, *ssq;
  int* cnt;
  double *cs, *st;
};

static void conv_pass(const WsPlan& P, const int* idx,
                      const float* Wa, const float* Wb,
                      const float* g1a, const float* b1a, const float* g1b, const float* b1b,
                      const float* g2a, const float* b2a,
                      hipStream_t stream){
  wtr2_kernel<<<dim3(10,12), 256, 0, stream>>>(Wa, Wb, P.Wt);
  // zero cs(320 f64) + st(256 f64) + ssq(384 f32) in one contiguous memset
  hipMemsetAsync(P.cs, 0, 320*8 + 256*8 + 384*4, stream);
  colsum_all<<<512, 256, 0, stream>>>(P.Abf, P.NBbf, P.cnt, P.cs);
  mean_kernel<<<6, 64, 0, stream>>>(P.cs, P.Wt, 384, P.mean);
  conv_gemm_v4<<<dim3(NM/128, 3), 256, 0, stream>>>(P.Abf, P.NBbf, idx, P.Wt, P.mean, P.big, P.ssq);
  apply_ga<<<N_ATOM/2, 256, 0, stream>>>(P.big, P.ssq, g1a, b1a, P.asum);
  asum_stats<<<64, 256, 0, stream>>>(P.asum, P.st);
  finalize_mr2<<<1, 128, 0, stream>>>(P.st, P.mr2);
  apply_out1<<<N_ATOM*128/256, 256, 0, stream>>>(P.Abf, P.asum, P.mr2, g2a, b2a);
  apply_gb<<<NM*64/256, 256, 0, stream>>>(P.big, P.NBbf, P.ssq, g1b, b1b);
}

extern "C" void kernel_launch(void* const* d_in, const int* in_sizes, int n_in,
                              void* d_out, int out_size, void* d_ws, size_t ws_size,
                              hipStream_t stream) {
  (void)in_sizes; (void)n_in; (void)out_size; (void)ws_size;
  const float* atom_fea   = (const float*)d_in[0];
  const float* nbr_fea    = (const float*)d_in[1];
  const int*   idx        = (const int*)d_in[2];
  const float* emb_atom_W = (const float*)d_in[4];
  const float* emb_atom_b = (const float*)d_in[5];
  const float* emb_bond_W = (const float*)d_in[6];
  const float* emb_bond_b = (const float*)d_in[7];
  const float* emb_atom2_W= (const float*)d_in[8];
  const float* emb_atom2_b= (const float*)d_in[9];
  const float* emb_bond2_W= (const float*)d_in[10];
  const float* emb_bond2_b= (const float*)d_in[11];
  const float* mu_W       = (const float*)d_in[12];
  const float* mu_b       = (const float*)d_in[13];
  const float* lv_W       = (const float*)d_in[14];
  const float* lv_b       = (const float*)d_in[15];
  const float* dec_W      = (const float*)d_in[16];
  const float* dec_b      = (const float*)d_in[17];
  const float* c1_Wa  = (const float*)d_in[18];
  const float* c1_Wb  = (const float*)d_in[19];
  const float* c1_g1a = (const float*)d_in[20];
  const float* c1_b1a = (const float*)d_in[21];
  const float* c1_g1b = (const float*)d_in[22];
  const float* c1_b1b = (const float*)d_in[23];
  const float* c1_g2a = (const float*)d_in[24];
  const float* c1_b2a = (const float*)d_in[25];
  const float* c2_Wa  = (const float*)d_in[26];
  const float* c2_Wb  = (const float*)d_in[27];
  const float* c2_g1a = (const float*)d_in[28];
  const float* c2_b1a = (const float*)d_in[29];
  const float* c2_g1b = (const float*)d_in[30];
  const float* c2_b1b = (const float*)d_in[31];
  const float* c2_g2a = (const float*)d_in[32];
  const float* c2_b2a = (const float*)d_in[33];

  float* out = (float*)d_out;

  WsPlan P;
  char* w = (char*)d_ws;
  auto alloc = [&](size_t bytes) -> char* {
    char* p = w; w += (bytes + 255) & ~(size_t)255; return p;
  };
  P.Abf    = (ushort_t*)alloc((size_t)N_ATOM*128*2);
  P.NBbf   = (ushort_t*)alloc((size_t)NM*64*2);
  P.big    = (__half*)  alloc((size_t)NM*384*2);
  P.asum   = (float*)   alloc((size_t)N_ATOM*128*4);
  P.pooled = (float*)   alloc(114688*4);
  P.fbuf   = (float*)   alloc(114688*4);
  P.Wt     = (ushort_t*)alloc(384*320*2);
  P.zws    = (float*)   alloc(256*4);
  P.eps    = (float*)   alloc(256*4);
  P.mean   = (float*)   alloc(384*4);
  P.mr2    = (float*)   alloc(256*4);
  P.cnt    = (int*)     alloc(N_ATOM*4);
  P.cs     = (double*)  alloc(320*8);   // cs, st, ssq contiguous (one memset)
  P.st     = (double*)  alloc(256*8);
  P.ssq    = (float*)   alloc(384*4);
  float* za2   = P.asum;                 // reuse after conv stacks
  float* bproj = (float*)P.big;          // reuse big in the final phase

  gen_eps_kernel<<<1, 256, 0, stream>>>(P.eps);
  tif_v2<<<21600, 256, 0, stream>>>(atom_fea, nbr_fea, idx, out + O_TIF);
  embed_atom_kernel<<<N_ATOM, 128, 0, stream>>>(atom_fea, emb_atom_W, emb_atom_b, P.Abf);
  embed_bond_kernel<<<NM/4, 256, 0, stream>>>(nbr_fea, emb_bond_W, emb_bond_b, P.NBbf);
  hipMemsetAsync(P.cnt, 0, N_ATOM*sizeof(int), stream);
  cnt_kernel<<<NM/256, 256, 0, stream>>>(idx, P.cnt);

  for (int L=0; L<3; ++L){
    conv_pass(P, idx, c1_Wa + (size_t)L*320*256, c1_Wb + (size_t)L*320*128,
              c1_g1a+L*256, c1_b1a+L*256, c1_g1b+L*128, c1_b1b+L*128,
              c1_g2a+L*128, c1_b2a+L*128, stream);
  }

  pool_a_kernel<<<NCRY, 128, 0, stream>>>(P.Abf, P.pooled);
  pool_n_kernel<<<NCRY, 768, 0, stream>>>(P.NBbf, P.pooled);
  muz_kernel<<<1, 256, 0, stream>>>(P.pooled, mu_W, mu_b, lv_W, lv_b, P.eps,
                                    out + O_MU, out + O_LV, out + O_Z, P.zws);
  compute_f_kernel<<<NCRY, 256, 0, stream>>>(P.zws, dec_W, dec_b, P.pooled, P.fbuf);
  dec_atom_kernel<<<N_ATOM*128/256, 256, 0, stream>>>(P.Abf, P.fbuf);
  dim3 gdb(N_ATOM, 3);
  dec_bond_kernel<<<gdb, 256, 0, stream>>>(P.NBbf, P.fbuf);

  for (int L=0; L<3; ++L){
    conv_pass(P, idx, c2_Wa + (size_t)L*320*256, c2_Wb + (size_t)L*320*128,
              c2_g1a+L*256, c2_b1a+L*256, c2_g1b+L*128, c2_b1b+L*128,
              c2_g2a+L*128, c2_b2a+L*128, stream);
  }

  embed_atom2_kernel<<<N_ATOM, 128, 0, stream>>>(P.Abf, emb_atom2_W, emb_atom2_b, za2);
  bproj_kernel<<<NM/6, 256, 0, stream>>>(P.NBbf, emb_bond2_W, emb_bond2_b, bproj);
  zdec_v2<<<21600, 256, 0, stream>>>(za2, bproj, idx, out + O_ZDEC);
}

// Round 7
// 3287.797 us; speedup vs baseline: 1.0361x; 1.0085x over previous
//
#include <hip/hip_runtime.h>
#include <hip/hip_bf16.h>
#include <hip/hip_fp16.h>
#include <cstdint>
#include <cstddef>

// ---------------- constants ----------------
#define N_ATOM 16384
#define M_NBR  12
#define NCRY   128
#define NM     (N_ATOM*M_NBR) // 196608

// output offsets (floats)
#define O_ZDEC 0
#define O_MU   44236800
#define O_LV   44237056
#define O_Z    44237312
#define O_TIF  44237568

typedef unsigned short ushort_t;
typedef float f32x4 __attribute__((ext_vector_type(4)));
typedef short bf16x8 __attribute__((ext_vector_type(8)));
typedef unsigned int u32x4 __attribute__((ext_vector_type(4)));

__device__ __forceinline__ float sigmoidf_(float x){ return 1.f/(1.f+__expf(-x)); }
__device__ __forceinline__ float softplusf_(float x){ return fmaxf(x,0.f) + log1pf(__expf(-fabsf(x))); }
__device__ __forceinline__ uint32_t rotl32_(uint32_t x, int r){ return (x<<r)|(x>>(32-r)); }
__device__ __forceinline__ float bf2f(ushort_t u){ return __uint_as_float(((uint32_t)u)<<16); }
__device__ __forceinline__ ushort_t f2bf(float x){
  uint32_t u = __float_as_uint(x);
  uint32_t r = (u + 0x7FFFu + ((u>>16)&1u)) >> 16;
  return (ushort_t)r;
}

// async global->LDS, 16B per lane; LDS dest = wave-uniform base + lane*16 (we pass
// per-lane pointers that are exactly base+lane*16, so first-lane readfirstlane is consistent)
#define GLDS16(g, l) __builtin_amdgcn_global_load_lds( \
    (const __attribute__((address_space(1))) void*)(g), \
    (__attribute__((address_space(3))) void*)(l), 16, 0, 0)

// ---------------- eps = jax.random.normal(key(42), (128,2)) ----------------
__global__ void gen_eps_kernel(float* __restrict__ eps){
  int j = threadIdx.x; // 256
  const uint32_t k0 = 0u, k1 = 42u;
  const uint32_t ks2 = k0 ^ k1 ^ 0x1BD11BDAu;
  uint32_t x0 = 0u + k0;
  uint32_t x1 = (uint32_t)j + k1;
#define RND_(r) { x0 += x1; x1 = rotl32_(x1, r); x1 ^= x0; }
  RND_(13) RND_(15) RND_(26) RND_(6)  x0 += k1;  x1 += ks2 + 1u;
  RND_(17) RND_(29) RND_(16) RND_(24) x0 += ks2; x1 += k0 + 2u;
  RND_(13) RND_(15) RND_(26) RND_(6)  x0 += k0;  x1 += k1 + 3u;
  RND_(17) RND_(29) RND_(16) RND_(24) x0 += k1;  x1 += ks2 + 4u;
  RND_(13) RND_(15) RND_(26) RND_(6)  x0 += ks2; x1 += k0 + 5u;
#undef RND_
  uint32_t bits = x0 ^ x1;
  float f = __uint_as_float((bits >> 9) | 0x3f800000u) - 1.0f;
  float u = __fadd_rn(__fmul_rn(f, 1.99999994f), -0.99999994f);
  u = fmaxf(-0.99999994f, u);
  float w = -log1pf(-u*u);
  float p;
  if (w < 5.0f){
    w -= 2.5f;
    p = 2.81022636e-08f;
    p = fmaf(p, w, 3.43273939e-07f);
    p = fmaf(p, w, -3.5233877e-06f);
    p = fmaf(p, w, -4.39150654e-06f);
    p = fmaf(p, w, 0.00021858087f);
    p = fmaf(p, w, -0.00125372503f);
    p = fmaf(p, w, -0.00417768164f);
    p = fmaf(p, w, 0.246640727f);
    p = fmaf(p, w, 1.50140941f);
  } else {
    w = sqrtf(w) - 3.0f;
    p = -0.000200214257f;
    p = fmaf(p, w, 0.000100950558f);
    p = fmaf(p, w, 0.00134934322f);
    p = fmaf(p, w, -0.00367342844f);
    p = fmaf(p, w, 0.00573950773f);
    p = fmaf(p, w, -0.0076224613f);
    p = fmaf(p, w, 0.00943887047f);
    p = fmaf(p, w, 1.00167406f);
    p = fmaf(p, w, 2.83297682f);
  }
  eps[j] = 1.41421356237f * (p * u);
}

// ---------------- total_input_fea output (coalesced) ------
__global__ void tif_v2(const float* __restrict__ atom, const float* __restrict__ nbr,
                       const int* __restrict__ idx, float* __restrict__ out){
  int e0 = blockIdx.x*2048 + threadIdx.x;
#pragma unroll
  for (int i=0;i<8;++i){
    int e = e0 + i*256;
    int r = e/225, c = e - r*225;
    float v;
    if (c < 92)       v = atom[(r/12)*92 + c];
    else if (c < 184) v = atom[idx[r]*92 + (c-92)];
    else              v = nbr[(size_t)r*41 + (c-184)];
    out[(size_t)e] = v;
  }
}

// ---------------- embeddings (write bf16 masters) ----------------
__global__ void embed_atom_kernel(const float* __restrict__ atom, const float* __restrict__ W,
                                  const float* __restrict__ bias, ushort_t* __restrict__ a0){
  __shared__ float row[92];
  int i = blockIdx.x; int t = threadIdx.x; // 128
  if (t < 92) row[t] = atom[i*92+t];
  __syncthreads();
  float s = bias[t];
#pragma unroll
  for (int k=0;k<92;++k) s = fmaf(row[k], W[k*128+t], s);
  a0[(size_t)i*128+t] = f2bf(s);
}

__global__ void embed_bond_kernel(const float* __restrict__ nbr, const float* __restrict__ W,
                                  const float* __restrict__ bias, ushort_t* __restrict__ nb0){
  __shared__ float rows[4][41];
  int r0 = blockIdx.x*4; int t = threadIdx.x; // 256
  if (t < 164) rows[t/41][t%41] = nbr[(size_t)r0*41 + t];
  __syncthreads();
  int rr = t >> 6, c = t & 63;
  float s = bias[c];
#pragma unroll
  for (int k=0;k<41;++k) s = fmaf(rows[rr][k], W[k*64+c], s);
  nb0[(size_t)(r0+rr)*64 + c] = f2bf(s);
}

// ---------------- idx histogram ----------------
__global__ void cnt_kernel(const int* __restrict__ idx, int* __restrict__ cnt){
  int e = blockIdx.x*256 + threadIdx.x;
  if (e < NM) atomicAdd(&cnt[idx[e]], 1);
}

// ---------------- weight transpose (Wa+Wb fused): Wt[o][k] = bf16(W[k][o]) ----------
__global__ void wtr2_kernel(const float* __restrict__ Wa, const float* __restrict__ Wb,
                            ushort_t* __restrict__ Wt){
  __shared__ ushort_t tile[32][33];
  int by = blockIdx.y;
  const float* W; int NO, o0, obase;
  if (by < 8){ W = Wa; NO = 256; o0 = by*32; obase = o0; }
  else       { W = Wb; NO = 128; o0 = (by-8)*32; obase = 256 + o0; }
  int k0 = blockIdx.x*32;
  int tx = threadIdx.x & 31, ty = threadIdx.x >> 5; // 256 thr
#pragma unroll
  for (int i = ty; i < 32; i += 8)
    tile[i][tx] = f2bf(W[(size_t)(k0+i)*NO + o0 + tx]);
  __syncthreads();
#pragma unroll
  for (int i = ty; i < 32; i += 8)
    Wt[(size_t)(obase+i)*320 + k0 + tx] = tile[tx][i];
}

// ---------------- fused column sums for exact mean ----------------
__global__ void colsum_all(const ushort_t* __restrict__ a, const ushort_t* __restrict__ nb,
                           const int* __restrict__ cnt, double* __restrict__ cs){
  int bx = blockIdx.x; int t = threadIdx.x; // 256
  if (bx < 128){
    int c = t & 127, h = t >> 7;
    float p1 = 0.f, p2 = 0.f;
    int i0 = bx*128;
    for (int i=i0+h; i<i0+128; i+=2){
      float v = bf2f(a[(size_t)i*128+c]);
      p1 += v;
      p2 += (float)cnt[i] * v;
    }
    atomicAdd(&cs[c], (double)p1);
    atomicAdd(&cs[128+c], (double)p2);
  } else {
    __shared__ float sh[4][64];
    int c = t & 63, pr = t >> 6;
    float p = 0.f;
    size_t r0 = (size_t)(bx-128) * 512;
    for (size_t r = r0 + pr; r < r0 + 512; r += 4) p += bf2f(nb[r*64 + c]);
    sh[pr][c] = p;
    __syncthreads();
    if (pr == 0){
      float s = sh[0][c]+sh[1][c]+sh[2][c]+sh[3][c];
      atomicAdd(&cs[256+c], (double)s);
    }
  }
}

__global__ void mean_kernel(const double* __restrict__ cs, const ushort_t* __restrict__ Wt,
                            int NO, float* __restrict__ mean){
  int o = blockIdx.x*64 + threadIdx.x;
  if (o >= NO) return;
  const ushort_t* wr = Wt + (size_t)o*320;
  double s = 0.0;
  for (int k=0;k<128;++k)   s += 12.0*cs[k]*(double)bf2f(wr[k]);
  for (int k=128;k<320;++k) s += cs[k]*(double)bf2f(wr[k]);
  mean[o] = (float)(s / (double)NM);
}

// ---------------- MFMA conv GEMM v5 (m97 structure: global_load_lds + NT stores) ----
// Block 128 rows x 128 cols, 4 waves (2x2), wave 64x64, BK=32 double-buffered.
// LDS layout linear [128 rows][4 chunks of 16B] per buffer; staged via global_load_lds.
__launch_bounds__(256, 3)
__global__ void conv_gemm_v5(const ushort_t* __restrict__ a_bf, const ushort_t* __restrict__ nb_bf,
                             const int* __restrict__ idx, const ushort_t* __restrict__ Wt,
                             const float* __restrict__ mean, __half* __restrict__ O,
                             float* __restrict__ ssq){
  __shared__ ushort_t sm[17408];   // As: 2x4096 @0, Bs: 2x4096 @8192; epilogue tile [128][136]
  __shared__ float sqred[128];
  ushort_t* As = sm;
  ushort_t* Bs = sm + 8192;
  const int t = threadIdx.x;
  const int lane = t & 63;
  const int w = t >> 6, wr = w >> 1, wc = w & 1;
  const int lm = lane & 15, lg = lane >> 4;
  const int row0 = blockIdx.x * 128, col0 = blockIdx.y * 128;

  const int rr0 = t >> 2, ch = t & 3;   // this thread stages chunks for rows rr0, rr0+64
  const int idxr0 = idx[row0 + rr0];
  const int idxr1 = idx[row0 + 64 + rr0];
  if (t < 128) sqred[t] = 0.f;

  auto stage = [&](int ks, int b_){
    ushort_t* Ad = As + b_*4096;
    ushort_t* Bd = Bs + b_*4096;
#pragma unroll
    for (int i=0;i<2;++i){
      int rr = rr0 + i*64;
      const ushort_t* ga;
      if (ks < 4)      ga = a_bf + (size_t)((row0+rr)/12)*128 + ks*32 + ch*8;
      else if (ks < 8) ga = a_bf + (size_t)(i ? idxr1 : idxr0)*128 + (ks-4)*32 + ch*8;
      else             ga = nb_bf + (size_t)(row0+rr)*64 + (ks-8)*32 + ch*8;
      GLDS16(ga, Ad + (t + i*256)*8);
      const ushort_t* gb = Wt + (size_t)(col0+rr)*320 + ks*32 + ch*8;
      GLDS16(gb, Bd + (t + i*256)*8);
    }
  };

  stage(0, 0);
  __syncthreads();   // compiler drains vmcnt before barrier -> buf0 ready

  f32x4 acc[4][4] = {};
  int buf = 0;
#pragma unroll
  for (int ks = 0; ks < 10; ++ks){
    if (ks < 9) stage(ks+1, buf^1);
    const ushort_t* Ab = As + buf*4096;
    const ushort_t* Bb = Bs + buf*4096;
    bf16x8 afr[4], bfr[4];
#pragma unroll
    for (int fm=0; fm<4; ++fm)
      afr[fm] = *(const bf16x8*)&Ab[(wr*64 + fm*16 + lm)*32 + lg*8];
#pragma unroll
    for (int fn=0; fn<4; ++fn)
      bfr[fn] = *(const bf16x8*)&Bb[(wc*64 + fn*16 + lm)*32 + lg*8];
#pragma unroll
    for (int fm=0; fm<4; ++fm)
#pragma unroll
      for (int fn=0; fn<4; ++fn)
        acc[fm][fn] = __builtin_amdgcn_mfma_f32_16x16x32_bf16(afr[fm], bfr[fn], acc[fm][fn], 0, 0, 0);
    __syncthreads();  // drains next-buf loads (vmcnt) + all ds reads (lgkm)
    buf ^= 1;
  }

  // epilogue: subtract exact mean, stage f16 tile in LDS, NT-store coalesced 256B runs
  float m4[4];
#pragma unroll
  for (int fn=0; fn<4; ++fn) m4[fn] = mean[col0 + wc*64 + fn*16 + lm];

#pragma unroll
  for (int fm=0; fm<4; ++fm){
    int rw = wr*64 + fm*16 + lg*4;
#pragma unroll
    for (int fn=0; fn<4; ++fn){
      int cl = wc*64 + fn*16 + lm;
#pragma unroll
      for (int j=0; j<4; ++j){
        float xc = acc[fm][fn][j] - m4[fn];
        __half h = __float2half(xc);
        sm[(rw+j)*136 + cl] = *(ushort_t*)&h;
      }
    }
  }
  __syncthreads();

  const int cch = t & 15, rb = t >> 4;
  float sq[8] = {0.f,0.f,0.f,0.f,0.f,0.f,0.f,0.f};
#pragma unroll
  for (int i=0; i<8; ++i){
    int row = rb + i*16;
    u32x4 v = *(const u32x4*)&sm[row*136 + cch*8];
    __builtin_nontemporal_store(v, (u32x4*)(O + (size_t)(row0+row)*384 + col0 + cch*8));
    const __half* hp = (const __half*)&v;
#pragma unroll
    for (int k=0;k<8;++k){
      float f = __half2float(hp[k]);
      sq[k] += f*f;
    }
  }
#pragma unroll
  for (int k=0;k<8;++k) atomicAdd(&sqred[cch*8+k], sq[k]);
  __syncthreads();
  if (t < 128) atomicAdd(&ssq[col0 + t], sqred[t]);
}

// ---------------- conv apply kernels (x centered: BN = x*rs*g + b; rs inline) ----
__global__ void apply_ga_v2(const __half* __restrict__ ga, const float* __restrict__ ssq,
                            const float* __restrict__ g1a, const float* __restrict__ b1a,
                            float* __restrict__ asum){
  int t = threadIdx.x;           // 256 = 16 atoms x 16 col-chunks
  int c8 = t & 15, al = t >> 4;
  int i = blockIdx.x*16 + al;
  int c0 = c8*8;
  float gf[8], bfv[8], gc[8], bcv[8];
#pragma unroll
  for (int k=0;k<8;++k){
    int c = c0+k;
    gf[k]  = g1a[c]     * rsqrtf(ssq[c]*(1.f/NM)+1e-5f);
    bfv[k] = b1a[c];
    gc[k]  = g1a[c+128] * rsqrtf(ssq[c+128]*(1.f/NM)+1e-5f);
    bcv[k] = b1a[c+128];
  }
  float s[8] = {0.f,0.f,0.f,0.f,0.f,0.f,0.f,0.f};
  size_t base = (size_t)i*12*384;
#pragma unroll
  for (int j=0;j<12;++j){
    u32x4 vf = __builtin_nontemporal_load((const u32x4*)(ga + base + j*384 + c0));
    u32x4 vc = __builtin_nontemporal_load((const u32x4*)(ga + base + j*384 + 128 + c0));
    const __half* hf = (const __half*)&vf;
    const __half* hc = (const __half*)&vc;
#pragma unroll
    for (int k=0;k<8;++k)
      s[k] += sigmoidf_(fmaf(__half2float(hf[k]), gf[k], bfv[k]))
            * softplusf_(fmaf(__half2float(hc[k]), gc[k], bcv[k]));
  }
  float* dst = asum + (size_t)i*128 + c0;
#pragma unroll
  for (int k=0;k<8;++k) dst[k] = s[k];
}

__global__ void asum_stats(const float* __restrict__ asum, double* __restrict__ st){
  int t = threadIdx.x; // 256
  int c = t & 127, h = t >> 7;
  float s1 = 0.f, s2 = 0.f;
  int i0 = blockIdx.x*256;
  for (int i=i0+h;i<i0+256;i+=2){
    float v = asum[(size_t)i*128+c];
    s1 += v; s2 += v*v;
  }
  atomicAdd(&st[c], (double)s1);
  atomicAdd(&st[128+c], (double)s2);
}

__global__ void finalize_mr2(const double* __restrict__ st, float* __restrict__ mr2){
  int c = threadIdx.x; // 128
  double mean = st[c] / (double)N_ATOM;
  double var  = st[128+c] / (double)N_ATOM - mean*mean;
  mr2[c]     = (float)mean;
  mr2[128+c] = rsqrtf((float)var + 1e-5f);
}

__global__ void apply_out1(ushort_t* __restrict__ a0, const float* __restrict__ asum,
                           const float* __restrict__ mr2, const float* __restrict__ g2a,
                           const float* __restrict__ b2a){
  int e = blockIdx.x*256 + threadIdx.x; // n*128
  int c = e & 127;
  float g = g2a[c]*mr2[128+c];
  float b = b2a[c] - mr2[c]*g;
  a0[e] = f2bf(softplusf_(bf2f(a0[e]) + fmaf(asum[e], g, b)));
}

__global__ void apply_gb_v2(const __half* __restrict__ gb, ushort_t* __restrict__ nb,
                            const float* __restrict__ ssq, const float* __restrict__ g1b,
                            const float* __restrict__ b1b){
  int t = threadIdx.x;          // 256 = 32 rows x 8 col-chunks
  int c8 = t & 7, rloc = t >> 3;
  int r = blockIdx.x*32 + rloc;
  int c0 = c8*8;
  float gf[8], bfv[8], gc[8], bcv[8];
#pragma unroll
  for (int k=0;k<8;++k){
    int c = c0+k;
    gf[k]  = g1b[c]    * rsqrtf(ssq[256+c]*(1.f/NM)+1e-5f);
    bfv[k] = b1b[c];
    gc[k]  = g1b[c+64] * rsqrtf(ssq[256+64+c]*(1.f/NM)+1e-5f);
    bcv[k] = b1b[c+64];
  }
  size_t gbase = (size_t)r*384 + 256;
  u32x4 vf = __builtin_nontemporal_load((const u32x4*)(gb + gbase + c0));
  u32x4 vc = __builtin_nontemporal_load((const u32x4*)(gb + gbase + 64 + c0));
  const __half* hf = (const __half*)&vf;
  const __half* hc = (const __half*)&vc;
  ushort_t* np = nb + (size_t)r*64 + c0;
  u32x4 old = *(const u32x4*)np;
  const ushort_t* op = (const ushort_t*)&old;
  u32x4 outv;
  ushort_t* ov = (ushort_t*)&outv;
#pragma unroll
  for (int k=0;k<8;++k){
    float x = bf2f(op[k]) + sigmoidf_(fmaf(__half2float(hf[k]), gf[k], bfv[k]))
                          * softplusf_(fmaf(__half2float(hc[k]), gc[k], bcv[k]));
    ov[k] = f2bf(softplusf_(x));
  }
  *(u32x4*)np = outv;
}

// ---------------- pooling / VAE / decode ----------------
__global__ void pool_a_kernel(const ushort_t* __restrict__ a, float* __restrict__ pooled){
  int b = blockIdx.x; int c = threadIdx.x; // 128
  float s = 0.f;
  for (int i=0;i<128;++i) s += bf2f(a[(size_t)((b<<7)+i)*128 + c]);
  pooled[b*896 + c] = softplusf_(s * (1.f/128.f));
}

__launch_bounds__(768)
__global__ void pool_n_kernel(const ushort_t* __restrict__ nb, float* __restrict__ pooled){
  int b = blockIdx.x; int t = threadIdx.x; // 768
  float s = 0.f;
  for (int i=0;i<128;++i) s += bf2f(nb[(size_t)((b<<7)+i)*768 + t]);
  pooled[b*896 + 128 + t] = softplusf_(s * (1.f/128.f));
}

__global__ void muz_kernel(const float* __restrict__ pooled, const float* __restrict__ muW,
                           const float* __restrict__ mub, const float* __restrict__ lvW,
                           const float* __restrict__ lvb, const float* __restrict__ eps,
                           float* __restrict__ out_mu, float* __restrict__ out_lv,
                           float* __restrict__ out_z, float* __restrict__ zws){
  int t = threadIdx.x; // 256 -> (b,l)
  int b = t >> 1, l = t & 1;
  const float* pr = pooled + b*896;
  float smu = mub[l], slv = lvb[l];
  for (int k=0;k<896;++k){
    float p = pr[k];
    smu = fmaf(p, muW[k*2+l], smu);
    slv = fmaf(p, lvW[k*2+l], slv);
  }
  out_mu[t] = smu; out_lv[t] = slv;
  float zv = fmaf(eps[t], __expf(0.5f*slv), smu);
  out_z[t] = zv; zws[t] = zv;
}

__global__ void compute_f_kernel(const float* __restrict__ zws, const float* __restrict__ decW,
                                 const float* __restrict__ decb, const float* __restrict__ pooled,
                                 float* __restrict__ f){
  int b = blockIdx.x;
  float z0 = zws[b*2], z1 = zws[b*2+1];
  for (int k = threadIdx.x; k < 896; k += 256){
    float zd = fmaf(z0, decW[k], fmaf(z1, decW[896+k], decb[k]));
    f[b*896+k] = zd / pooled[b*896+k];
  }
}

__global__ void dec_atom_kernel(ushort_t* __restrict__ a, const float* __restrict__ f){
  int e = blockIdx.x*256+threadIdx.x; // n*128
  int c = e & 127; int b = e >> 14;
  a[e] = f2bf(softplusf_(bf2f(a[e]) * f[b*896 + c]));
}

__global__ void dec_bond_kernel(ushort_t* __restrict__ nb, const float* __restrict__ f){
  int i = blockIdx.x; int off = blockIdx.y*256 + threadIdx.x; // off < 768
  int b = i >> 7;
  size_t e = (size_t)i*768 + off;
  nb[e] = f2bf(softplusf_(bf2f(nb[e]) * f[b*896 + 128 + off]));
}

// ---------------- final embeddings ----------------
__global__ void embed_atom2_kernel(const ushort_t* __restrict__ a, const float* __restrict__ W,
                                   const float* __restrict__ bias, float* __restrict__ za2){
  __shared__ float row[128];
  int i = blockIdx.x; int t = threadIdx.x; // 128
  row[t] = bf2f(a[(size_t)i*128+t]);
  __syncthreads();
  if (t < 92){
    float s = bias[t];
#pragma unroll
    for (int k=0;k<128;++k) s = fmaf(row[k], W[k*92+t], s);
    za2[(size_t)i*92+t] = sigmoidf_(s);
  }
}

__global__ void bproj_kernel(const ushort_t* __restrict__ nb, const float* __restrict__ W,
                             const float* __restrict__ bias, float* __restrict__ bp){
  __shared__ float Ws[64][41];
  __shared__ float rows[6][64];
  int t = threadIdx.x; // 256
  for (int e=t; e<64*41; e+=256) Ws[e/41][e%41] = W[e];
  int r0 = blockIdx.x*6;
  for (int e=t; e<6*64; e+=256){
    int rr = e>>6, c = e&63;
    rows[rr][c] = bf2f(nb[(size_t)(r0+rr)*64 + c]);
  }
  __syncthreads();
  if (t < 246){
    int rr = t/41, o = t - rr*41;
    float s = bias[o];
#pragma unroll
    for (int k=0;k<64;++k) s = fmaf(rows[rr][k], Ws[k][o], s);
    bp[(size_t)(r0+rr)*41 + o] = sigmoidf_(s);
  }
}

__global__ void zdec_v2(const float* __restrict__ za2, const float* __restrict__ bp,
                        const int* __restrict__ idx, float* __restrict__ out){
  int e0 = blockIdx.x*2048 + threadIdx.x;
#pragma unroll
  for (int i=0;i<8;++i){
    int e = e0 + i*256;
    int r = e/225, c = e - r*225;
    float v;
    if (c < 92)       v = za2[(size_t)(r/12)*92 + c];
    else if (c < 184) v = za2[(size_t)idx[r]*92 + (c-92)];
    else              v = bp[(size_t)r*41 + (c-184)];
    out[(size_t)e] = v;
  }
}

// ---------------- host side ----------------
struct WsPlan {
  ushort_t *Abf, *NBbf, *Wt;
  __half* big;
  float *asum, *pooled, *fbuf, *zws, *eps, *mean, *mr2, *ssq;
  int* cnt;
  double *cs, *st;
};

static void conv_pass(const WsPlan& P, const int* idx,
                      const float* Wa, const float* Wb,
                      const float* g1a, const float* b1a, const float* g1b, const float* b1b,
                      const float* g2a, const float* b2a,
                      hipStream_t stream){
  wtr2_kernel<<<dim3(10,12), 256, 0, stream>>>(Wa, Wb, P.Wt);
  // zero cs(320 f64) + st(256 f64) + ssq(384 f32) in one contiguous memset
  hipMemsetAsync(P.cs, 0, 320*8 + 256*8 + 384*4, stream);
  colsum_all<<<512, 256, 0, stream>>>(P.Abf, P.NBbf, P.cnt, P.cs);
  mean_kernel<<<6, 64, 0, stream>>>(P.cs, P.Wt, 384, P.mean);
  conv_gemm_v5<<<dim3(NM/128, 3), 256, 0, stream>>>(P.Abf, P.NBbf, idx, P.Wt, P.mean, P.big, P.ssq);
  apply_ga_v2<<<N_ATOM/16, 256, 0, stream>>>(P.big, P.ssq, g1a, b1a, P.asum);
  asum_stats<<<64, 256, 0, stream>>>(P.asum, P.st);
  finalize_mr2<<<1, 128, 0, stream>>>(P.st, P.mr2);
  apply_out1<<<N_ATOM*128/256, 256, 0, stream>>>(P.Abf, P.asum, P.mr2, g2a, b2a);
  apply_gb_v2<<<NM/32, 256, 0, stream>>>(P.big, P.NBbf, P.ssq, g1b, b1b);
}

extern "C" void kernel_launch(void* const* d_in, const int* in_sizes, int n_in,
                              void* d_out, int out_size, void* d_ws, size_t ws_size,
                              hipStream_t stream) {
  (void)in_sizes; (void)n_in; (void)out_size; (void)ws_size;
  const float* atom_fea   = (const float*)d_in[0];
  const float* nbr_fea    = (const float*)d_in[1];
  const int*   idx        = (const int*)d_in[2];
  const float* emb_atom_W = (const float*)d_in[4];
  const float* emb_atom_b = (const float*)d_in[5];
  const float* emb_bond_W = (const float*)d_in[6];
  const float* emb_bond_b = (const float*)d_in[7];
  const float* emb_atom2_W= (const float*)d_in[8];
  const float* emb_atom2_b= (const float*)d_in[9];
  const float* emb_bond2_W= (const float*)d_in[10];
  const float* emb_bond2_b= (const float*)d_in[11];
  const float* mu_W       = (const float*)d_in[12];
  const float* mu_b       = (const float*)d_in[13];
  const float* lv_W       = (const float*)d_in[14];
  const float* lv_b       = (const float*)d_in[15];
  const float* dec_W      = (const float*)d_in[16];
  const float* dec_b      = (const float*)d_in[17];
  const float* c1_Wa  = (const float*)d_in[18];
  const float* c1_Wb  = (const float*)d_in[19];
  const float* c1_g1a = (const float*)d_in[20];
  const float* c1_b1a = (const float*)d_in[21];
  const float* c1_g1b = (const float*)d_in[22];
  const float* c1_b1b = (const float*)d_in[23];
  const float* c1_g2a = (const float*)d_in[24];
  const float* c1_b2a = (const float*)d_in[25];
  const float* c2_Wa  = (const float*)d_in[26];
  const float* c2_Wb  = (const float*)d_in[27];
  const float* c2_g1a = (const float*)d_in[28];
  const float* c2_b1a = (const float*)d_in[29];
  const float* c2_g1b = (const float*)d_in[30];
  const float* c2_b1b = (const float*)d_in[31];
  const float* c2_g2a = (const float*)d_in[32];
  const float* c2_b2a = (const float*)d_in[33];

  float* out = (float*)d_out;

  WsPlan P;
  char* w = (char*)d_ws;
  auto alloc = [&](size_t bytes) -> char* {
    char* p = w; w += (bytes + 255) & ~(size_t)255; return p;
  };
  P.Abf    = (ushort_t*)alloc((size_t)N_ATOM*128*2);
  P.NBbf   = (ushort_t*)alloc((size_t)NM*64*2);
  P.big    = (__half*)  alloc((size_t)NM*384*2);
  P.asum   = (float*)   alloc((size_t)N_ATOM*128*4);
  P.pooled = (float*)   alloc(114688*4);
  P.fbuf   = (float*)   alloc(114688*4);
  P.Wt     = (ushort_t*)alloc(384*320*2);
  P.zws    = (float*)   alloc(256*4);
  P.eps    = (float*)   alloc(256*4);
  P.mean   = (float*)   alloc(384*4);
  P.mr2    = (float*)   alloc(256*4);
  P.cnt    = (int*)     alloc(N_ATOM*4);
  P.cs     = (double*)  alloc(320*8);   // cs, st, ssq contiguous (one memset)
  P.st     = (double*)  alloc(256*8);
  P.ssq    = (float*)   alloc(384*4);
  float* za2   = P.asum;                 // reuse after conv stacks
  float* bproj = (float*)P.big;          // reuse big in the final phase

  gen_eps_kernel<<<1, 256, 0, stream>>>(P.eps);
  tif_v2<<<21600, 256, 0, stream>>>(atom_fea, nbr_fea, idx, out + O_TIF);
  embed_atom_kernel<<<N_ATOM, 128, 0, stream>>>(atom_fea, emb_atom_W, emb_atom_b, P.Abf);
  embed_bond_kernel<<<NM/4, 256, 0, stream>>>(nbr_fea, emb_bond_W, emb_bond_b, P.NBbf);
  hipMemsetAsync(P.cnt, 0, N_ATOM*sizeof(int), stream);
  cnt_kernel<<<NM/256, 256, 0, stream>>>(idx, P.cnt);

  for (int L=0; L<3; ++L){
    conv_pass(P, idx, c1_Wa + (size_t)L*320*256, c1_Wb + (size_t)L*320*128,
              c1_g1a+L*256, c1_b1a+L*256, c1_g1b+L*128, c1_b1b+L*128,
              c1_g2a+L*128, c1_b2a+L*128, stream);
  }

  pool_a_kernel<<<NCRY, 128, 0, stream>>>(P.Abf, P.pooled);
  pool_n_kernel<<<NCRY, 768, 0, stream>>>(P.NBbf, P.pooled);
  muz_kernel<<<1, 256, 0, stream>>>(P.pooled, mu_W, mu_b, lv_W, lv_b, P.eps,
                                    out + O_MU, out + O_LV, out + O_Z, P.zws);
  compute_f_kernel<<<NCRY, 256, 0, stream>>>(P.zws, dec_W, dec_b, P.pooled, P.fbuf);
  dec_atom_kernel<<<N_ATOM*128/256, 256, 0, stream>>>(P.Abf, P.fbuf);
  dim3 gdb(N_ATOM, 3);
  dec_bond_kernel<<<gdb, 256, 0, stream>>>(P.NBbf, P.fbuf);

  for (int L=0; L<3; ++L){
    conv_pass(P, idx, c2_Wa + (size_t)L*320*256, c2_Wb + (size_t)L*320*128,
              c2_g1a+L*256, c2_b1a+L*256, c2_g1b+L*128, c2_b1b+L*128,
              c2_g2a+L*128, c2_b2a+L*128, stream);
  }

  embed_atom2_kernel<<<N_ATOM, 128, 0, stream>>>(P.Abf, emb_atom2_W, emb_atom2_b, za2);
  bproj_kernel<<<NM/6, 256, 0, stream>>>(P.NBbf, emb_bond2_W, emb_bond2_b, bproj);
  zdec_v2<<<21600, 256, 0, stream>>>(za2, bproj, idx, out + O_ZDEC);
}

// Round 8
// 3235.560 us; speedup vs baseline: 1.0528x; 1.0161x over previous
//
#include <hip/hip_runtime.h>
#include <hip/hip_bf16.h>
#include <hip/hip_fp16.h>
#include <cstdint>
#include <cstddef>

// ---------------- constants ----------------
#define N_ATOM 16384
#define M_NBR  12
#define NCRY   128
#define NM     (N_ATOM*M_NBR) // 196608

// output offsets (floats)
#define O_ZDEC 0
#define O_MU   44236800
#define O_LV   44237056
#define O_Z    44237312
#define O_TIF  44237568

typedef unsigned short ushort_t;
typedef float f32x4 __attribute__((ext_vector_type(4)));
typedef short bf16x8 __attribute__((ext_vector_type(8)));
typedef unsigned int u32x4 __attribute__((ext_vector_type(4)));

__device__ __forceinline__ float sigmoidf_(float x){ return 1.f/(1.f+__expf(-x)); }
__device__ __forceinline__ float softplusf_(float x){ return fmaxf(x,0.f) + log1pf(__expf(-fabsf(x))); }
__device__ __forceinline__ uint32_t rotl32_(uint32_t x, int r){ return (x<<r)|(x>>(32-r)); }
__device__ __forceinline__ float bf2f(ushort_t u){ return __uint_as_float(((uint32_t)u)<<16); }
__device__ __forceinline__ ushort_t f2bf(float x){
  uint32_t u = __float_as_uint(x);
  uint32_t r = (u + 0x7FFFu + ((u>>16)&1u)) >> 16;
  return (ushort_t)r;
}

// async global->LDS, 16B per lane; LDS dest = wave-uniform base + lane*16
#define GLDS16(g, l) __builtin_amdgcn_global_load_lds( \
    (const __attribute__((address_space(1))) void*)(g), \
    (__attribute__((address_space(3))) void*)(l), 16, 0, 0)

// ---------------- eps = jax.random.normal(key(42), (128,2)) ----------------
__global__ void gen_eps_kernel(float* __restrict__ eps){
  int j = threadIdx.x; // 256
  const uint32_t k0 = 0u, k1 = 42u;
  const uint32_t ks2 = k0 ^ k1 ^ 0x1BD11BDAu;
  uint32_t x0 = 0u + k0;
  uint32_t x1 = (uint32_t)j + k1;
#define RND_(r) { x0 += x1; x1 = rotl32_(x1, r); x1 ^= x0; }
  RND_(13) RND_(15) RND_(26) RND_(6)  x0 += k1;  x1 += ks2 + 1u;
  RND_(17) RND_(29) RND_(16) RND_(24) x0 += ks2; x1 += k0 + 2u;
  RND_(13) RND_(15) RND_(26) RND_(6)  x0 += k0;  x1 += k1 + 3u;
  RND_(17) RND_(29) RND_(16) RND_(24) x0 += k1;  x1 += ks2 + 4u;
  RND_(13) RND_(15) RND_(26) RND_(6)  x0 += ks2; x1 += k0 + 5u;
#undef RND_
  uint32_t bits = x0 ^ x1;
  float f = __uint_as_float((bits >> 9) | 0x3f800000u) - 1.0f;
  float u = __fadd_rn(__fmul_rn(f, 1.99999994f), -0.99999994f);
  u = fmaxf(-0.99999994f, u);
  float w = -log1pf(-u*u);
  float p;
  if (w < 5.0f){
    w -= 2.5f;
    p = 2.81022636e-08f;
    p = fmaf(p, w, 3.43273939e-07f);
    p = fmaf(p, w, -3.5233877e-06f);
    p = fmaf(p, w, -4.39150654e-06f);
    p = fmaf(p, w, 0.00021858087f);
    p = fmaf(p, w, -0.00125372503f);
    p = fmaf(p, w, -0.00417768164f);
    p = fmaf(p, w, 0.246640727f);
    p = fmaf(p, w, 1.50140941f);
  } else {
    w = sqrtf(w) - 3.0f;
    p = -0.000200214257f;
    p = fmaf(p, w, 0.000100950558f);
    p = fmaf(p, w, 0.00134934322f);
    p = fmaf(p, w, -0.00367342844f);
    p = fmaf(p, w, 0.00573950773f);
    p = fmaf(p, w, -0.0076224613f);
    p = fmaf(p, w, 0.00943887047f);
    p = fmaf(p, w, 1.00167406f);
    p = fmaf(p, w, 2.83297682f);
  }
  eps[j] = 1.41421356237f * (p * u);
}

// ---------------- total_input_fea output (coalesced, NT stores) ------
__global__ void tif_v2(const float* __restrict__ atom, const float* __restrict__ nbr,
                       const int* __restrict__ idx, float* __restrict__ out){
  int e0 = blockIdx.x*2048 + threadIdx.x;
#pragma unroll
  for (int i=0;i<8;++i){
    int e = e0 + i*256;
    int r = e/225, c = e - r*225;
    float v;
    if (c < 92)       v = atom[(r/12)*92 + c];
    else if (c < 184) v = atom[idx[r]*92 + (c-92)];
    else              v = nbr[(size_t)r*41 + (c-184)];
    __builtin_nontemporal_store(v, out + (size_t)e);
  }
}

// ---------------- embeddings (write bf16 masters) ----------------
__global__ void embed_atom_kernel(const float* __restrict__ atom, const float* __restrict__ W,
                                  const float* __restrict__ bias, ushort_t* __restrict__ a0){
  __shared__ float row[92];
  int i = blockIdx.x; int t = threadIdx.x; // 128
  if (t < 92) row[t] = atom[i*92+t];
  __syncthreads();
  float s = bias[t];
#pragma unroll
  for (int k=0;k<92;++k) s = fmaf(row[k], W[k*128+t], s);
  a0[(size_t)i*128+t] = f2bf(s);
}

__global__ void embed_bond_kernel(const float* __restrict__ nbr, const float* __restrict__ W,
                                  const float* __restrict__ bias, ushort_t* __restrict__ nb0){
  __shared__ float rows[4][41];
  int r0 = blockIdx.x*4; int t = threadIdx.x; // 256
  if (t < 164) rows[t/41][t%41] = nbr[(size_t)r0*41 + t];
  __syncthreads();
  int rr = t >> 6, c = t & 63;
  float s = bias[c];
#pragma unroll
  for (int k=0;k<41;++k) s = fmaf(rows[rr][k], W[k*64+c], s);
  nb0[(size_t)(r0+rr)*64 + c] = f2bf(s);
}

// ---------------- idx histogram ----------------
__global__ void cnt_kernel(const int* __restrict__ idx, int* __restrict__ cnt){
  int e = blockIdx.x*256 + threadIdx.x;
  if (e < NM) atomicAdd(&cnt[idx[e]], 1);
}

// ---------------- weight transpose (Wa+Wb fused) + stats zeroing ----------
__global__ void wtr2_kernel(const float* __restrict__ Wa, const float* __restrict__ Wb,
                            ushort_t* __restrict__ Wt, float* __restrict__ zstats){
  __shared__ ushort_t tile[32][33];
  // block (0,0) also zeroes cs(320 f64) + st(256 f64) + ssq(384 f32) = 1536 f32
  if (blockIdx.x == 0 && blockIdx.y == 0){
#pragma unroll
    for (int k=0;k<6;++k) zstats[threadIdx.x + k*256] = 0.f;
  }
  int by = blockIdx.y;
  const float* W; int NO, o0, obase;
  if (by < 8){ W = Wa; NO = 256; o0 = by*32; obase = o0; }
  else       { W = Wb; NO = 128; o0 = (by-8)*32; obase = 256 + o0; }
  int k0 = blockIdx.x*32;
  int tx = threadIdx.x & 31, ty = threadIdx.x >> 5; // 256 thr
#pragma unroll
  for (int i = ty; i < 32; i += 8)
    tile[i][tx] = f2bf(W[(size_t)(k0+i)*NO + o0 + tx]);
  __syncthreads();
#pragma unroll
  for (int i = ty; i < 32; i += 8)
    Wt[(size_t)(obase+i)*320 + k0 + tx] = tile[tx][i];
}

// ---------------- fused column sums for exact mean ----------------
__global__ void colsum_all(const ushort_t* __restrict__ a, const ushort_t* __restrict__ nb,
                           const int* __restrict__ cnt, double* __restrict__ cs){
  int bx = blockIdx.x; int t = threadIdx.x; // 256
  if (bx < 128){
    int c = t & 127, h = t >> 7;
    float p1 = 0.f, p2 = 0.f;
    int i0 = bx*128;
    for (int i=i0+h; i<i0+128; i+=2){
      float v = bf2f(a[(size_t)i*128+c]);
      p1 += v;
      p2 += (float)cnt[i] * v;
    }
    atomicAdd(&cs[c], (double)p1);
    atomicAdd(&cs[128+c], (double)p2);
  } else {
    __shared__ float sh[4][64];
    int c = t & 63, pr = t >> 6;
    float p = 0.f;
    size_t r0 = (size_t)(bx-128) * 512;
    for (size_t r = r0 + pr; r < r0 + 512; r += 4) p += bf2f(nb[r*64 + c]);
    sh[pr][c] = p;
    __syncthreads();
    if (pr == 0){
      float s = sh[0][c]+sh[1][c]+sh[2][c]+sh[3][c];
      atomicAdd(&cs[256+c], (double)s);
    }
  }
}

__global__ void mean_kernel(const double* __restrict__ cs, const ushort_t* __restrict__ Wt,
                            int NO, float* __restrict__ mean){
  int o = blockIdx.x*64 + threadIdx.x;
  if (o >= NO) return;
  const ushort_t* wr = Wt + (size_t)o*320;
  double s = 0.0;
  for (int k=0;k<128;++k)   s += 12.0*cs[k]*(double)bf2f(wr[k]);
  for (int k=128;k<320;++k) s += cs[k]*(double)bf2f(wr[k]);
  mean[o] = (float)(s / (double)NM);
}

// ---------------- MFMA conv GEMM v6: col-block-major output [3][NM][128] ----
// Block 128 rows x 128 cols, 4 waves (2x2), wave 64x64, BK=32 double-buffered,
// global_load_lds staging. Each block streams a CONTIGUOUS 32KB output region.
__launch_bounds__(256, 3)
__global__ void conv_gemm_v6(const ushort_t* __restrict__ a_bf, const ushort_t* __restrict__ nb_bf,
                             const int* __restrict__ idx, const ushort_t* __restrict__ Wt,
                             const float* __restrict__ mean, __half* __restrict__ O,
                             float* __restrict__ ssq){
  __shared__ ushort_t sm[17408];   // As: 2x4096 @0, Bs: 2x4096 @8192; epilogue tile [128][136]
  __shared__ float sqred[128];
  ushort_t* As = sm;
  ushort_t* Bs = sm + 8192;
  const int t = threadIdx.x;
  const int lane = t & 63;
  const int w = t >> 6, wr = w >> 1, wc = w & 1;
  const int lm = lane & 15, lg = lane >> 4;
  const int row0 = blockIdx.x * 128;
  const int cb   = blockIdx.y;          // col-block 0..2
  const int col0 = cb * 128;
  __half* Ob = O + (size_t)cb * ((size_t)NM*128);

  const int rr0 = t >> 2, ch = t & 3;
  const int idxr0 = idx[row0 + rr0];
  const int idxr1 = idx[row0 + 64 + rr0];
  if (t < 128) sqred[t] = 0.f;

  auto stage = [&](int ks, int b_){
    ushort_t* Ad = As + b_*4096;
    ushort_t* Bd = Bs + b_*4096;
#pragma unroll
    for (int i=0;i<2;++i){
      int rr = rr0 + i*64;
      const ushort_t* ga;
      if (ks < 4)      ga = a_bf + (size_t)((row0+rr)/12)*128 + ks*32 + ch*8;
      else if (ks < 8) ga = a_bf + (size_t)(i ? idxr1 : idxr0)*128 + (ks-4)*32 + ch*8;
      else             ga = nb_bf + (size_t)(row0+rr)*64 + (ks-8)*32 + ch*8;
      GLDS16(ga, Ad + (t + i*256)*8);
      const ushort_t* gb = Wt + (size_t)(col0+rr)*320 + ks*32 + ch*8;
      GLDS16(gb, Bd + (t + i*256)*8);
    }
  };

  stage(0, 0);
  __syncthreads();

  f32x4 acc[4][4] = {};
  int buf = 0;
#pragma unroll
  for (int ks = 0; ks < 10; ++ks){
    if (ks < 9) stage(ks+1, buf^1);
    const ushort_t* Ab = As + buf*4096;
    const ushort_t* Bb = Bs + buf*4096;
    bf16x8 afr[4], bfr[4];
#pragma unroll
    for (int fm=0; fm<4; ++fm)
      afr[fm] = *(const bf16x8*)&Ab[(wr*64 + fm*16 + lm)*32 + lg*8];
#pragma unroll
    for (int fn=0; fn<4; ++fn)
      bfr[fn] = *(const bf16x8*)&Bb[(wc*64 + fn*16 + lm)*32 + lg*8];
#pragma unroll
    for (int fm=0; fm<4; ++fm)
#pragma unroll
      for (int fn=0; fn<4; ++fn)
        acc[fm][fn] = __builtin_amdgcn_mfma_f32_16x16x32_bf16(afr[fm], bfr[fn], acc[fm][fn], 0, 0, 0);
    __syncthreads();
    buf ^= 1;
  }

  // epilogue: subtract exact mean, stage f16 tile in LDS, contiguous NT stores
  float m4[4];
#pragma unroll
  for (int fn=0; fn<4; ++fn) m4[fn] = mean[col0 + wc*64 + fn*16 + lm];

#pragma unroll
  for (int fm=0; fm<4; ++fm){
    int rw = wr*64 + fm*16 + lg*4;
#pragma unroll
    for (int fn=0; fn<4; ++fn){
      int cl = wc*64 + fn*16 + lm;
#pragma unroll
      for (int j=0; j<4; ++j){
        float xc = acc[fm][fn][j] - m4[fn];
        __half h = __float2half(xc);
        sm[(rw+j)*136 + cl] = *(ushort_t*)&h;
      }
    }
  }
  __syncthreads();

  const int cch = t & 15, rb = t >> 4;
  float sq[8] = {0.f,0.f,0.f,0.f,0.f,0.f,0.f,0.f};
#pragma unroll
  for (int i=0; i<8; ++i){
    int row = rb + i*16;
    u32x4 v = *(const u32x4*)&sm[row*136 + cch*8];
    __builtin_nontemporal_store(v, (u32x4*)(Ob + (size_t)(row0+row)*128 + cch*8));
    const __half* hp = (const __half*)&v;
#pragma unroll
    for (int k=0;k<8;++k){
      float f = __half2float(hp[k]);
      sq[k] += f*f;
    }
  }
#pragma unroll
  for (int k=0;k<8;++k) atomicAdd(&sqred[cch*8+k], sq[k]);
  __syncthreads();
  if (t < 128) atomicAdd(&ssq[col0 + t], sqred[t]);
}

// ---------------- conv apply kernels (x centered: BN = x*rs*g + b; rs inline) ----
// ga lives in O0 (cols 0-127) and O1 (cols 128-255), each [NM][128]
__global__ void apply_ga_v3(const __half* __restrict__ O0, const __half* __restrict__ O1,
                            const float* __restrict__ ssq,
                            const float* __restrict__ g1a, const float* __restrict__ b1a,
                            float* __restrict__ asum){
  int t = threadIdx.x;           // 256 = 16 atoms x 16 col-chunks
  int c8 = t & 15, al = t >> 4;
  int i = blockIdx.x*16 + al;
  int c0 = c8*8;
  float gf[8], bfv[8], gc[8], bcv[8];
#pragma unroll
  for (int k=0;k<8;++k){
    int c = c0+k;
    gf[k]  = g1a[c]     * rsqrtf(ssq[c]*(1.f/NM)+1e-5f);
    bfv[k] = b1a[c];
    gc[k]  = g1a[c+128] * rsqrtf(ssq[c+128]*(1.f/NM)+1e-5f);
    bcv[k] = b1a[c+128];
  }
  float s[8] = {0.f,0.f,0.f,0.f,0.f,0.f,0.f,0.f};
  size_t base = (size_t)i*12*128;
#pragma unroll
  for (int j=0;j<12;++j){
    u32x4 vf = __builtin_nontemporal_load((const u32x4*)(O0 + base + j*128 + c0));
    u32x4 vc = __builtin_nontemporal_load((const u32x4*)(O1 + base + j*128 + c0));
    const __half* hf = (const __half*)&vf;
    const __half* hc = (const __half*)&vc;
#pragma unroll
    for (int k=0;k<8;++k)
      s[k] += sigmoidf_(fmaf(__half2float(hf[k]), gf[k], bfv[k]))
            * softplusf_(fmaf(__half2float(hc[k]), gc[k], bcv[k]));
  }
  float* dst = asum + (size_t)i*128 + c0;
#pragma unroll
  for (int k=0;k<8;++k) dst[k] = s[k];
}

__global__ void asum_stats(const float* __restrict__ asum, double* __restrict__ st){
  int t = threadIdx.x; // 256
  int c = t & 127, h = t >> 7;
  float s1 = 0.f, s2 = 0.f;
  int i0 = blockIdx.x*256;
  for (int i=i0+h;i<i0+256;i+=2){
    float v = asum[(size_t)i*128+c];
    s1 += v; s2 += v*v;
  }
  atomicAdd(&st[c], (double)s1);
  atomicAdd(&st[128+c], (double)s2);
}

// apply_out1 with inline mr2 (computes mean/rs of asum from st)
__global__ void apply_out1_v2(ushort_t* __restrict__ a0, const float* __restrict__ asum,
                              const double* __restrict__ st, const float* __restrict__ g2a,
                              const float* __restrict__ b2a){
  int e = blockIdx.x*256 + threadIdx.x; // n*128
  int c = e & 127;
  double mean = st[c] * (1.0/N_ATOM);
  double var  = st[128+c] * (1.0/N_ATOM) - mean*mean;
  float rs = rsqrtf((float)var + 1e-5f);
  float g = g2a[c]*rs;
  float b = b2a[c] - (float)mean*g;
  a0[e] = f2bf(softplusf_(bf2f(a0[e]) + fmaf(asum[e], g, b)));
}

// gb lives in O2, [NM][128] (filter 0-63, core 64-127)
__global__ void apply_gb_v3(const __half* __restrict__ O2, ushort_t* __restrict__ nb,
                            const float* __restrict__ ssq, const float* __restrict__ g1b,
                            const float* __restrict__ b1b){
  int t = threadIdx.x;          // 256 = 32 rows x 8 col-chunks
  int c8 = t & 7, rloc = t >> 3;
  int r = blockIdx.x*32 + rloc;
  int c0 = c8*8;
  float gf[8], bfv[8], gc[8], bcv[8];
#pragma unroll
  for (int k=0;k<8;++k){
    int c = c0+k;
    gf[k]  = g1b[c]    * rsqrtf(ssq[256+c]*(1.f/NM)+1e-5f);
    bfv[k] = b1b[c];
    gc[k]  = g1b[c+64] * rsqrtf(ssq[256+64+c]*(1.f/NM)+1e-5f);
    bcv[k] = b1b[c+64];
  }
  size_t gbase = (size_t)r*128;
  u32x4 vf = __builtin_nontemporal_load((const u32x4*)(O2 + gbase + c0));
  u32x4 vc = __builtin_nontemporal_load((const u32x4*)(O2 + gbase + 64 + c0));
  const __half* hf = (const __half*)&vf;
  const __half* hc = (const __half*)&vc;
  ushort_t* np = nb + (size_t)r*64 + c0;
  u32x4 old = *(const u32x4*)np;
  const ushort_t* op = (const ushort_t*)&old;
  u32x4 outv;
  ushort_t* ov = (ushort_t*)&outv;
#pragma unroll
  for (int k=0;k<8;++k){
    float x = bf2f(op[k]) + sigmoidf_(fmaf(__half2float(hf[k]), gf[k], bfv[k]))
                          * softplusf_(fmaf(__half2float(hc[k]), gc[k], bcv[k]));
    ov[k] = f2bf(softplusf_(x));
  }
  *(u32x4*)np = outv;
}

// ---------------- pooling / VAE / decode ----------------
__global__ void pool_a_kernel(const ushort_t* __restrict__ a, float* __restrict__ pooled){
  int b = blockIdx.x; int c = threadIdx.x; // 128
  float s = 0.f;
  for (int i=0;i<128;++i) s += bf2f(a[(size_t)((b<<7)+i)*128 + c]);
  pooled[b*896 + c] = softplusf_(s * (1.f/128.f));
}

__launch_bounds__(768)
__global__ void pool_n_kernel(const ushort_t* __restrict__ nb, float* __restrict__ pooled){
  int b = blockIdx.x; int t = threadIdx.x; // 768
  float s = 0.f;
  for (int i=0;i<128;++i) s += bf2f(nb[(size_t)((b<<7)+i)*768 + t]);
  pooled[b*896 + 128 + t] = softplusf_(s * (1.f/128.f));
}

__global__ void muz_kernel(const float* __restrict__ pooled, const float* __restrict__ muW,
                           const float* __restrict__ mub, const float* __restrict__ lvW,
                           const float* __restrict__ lvb, const float* __restrict__ eps,
                           float* __restrict__ out_mu, float* __restrict__ out_lv,
                           float* __restrict__ out_z, float* __restrict__ zws){
  int t = threadIdx.x; // 256 -> (b,l)
  int b = t >> 1, l = t & 1;
  const float* pr = pooled + b*896;
  float smu = mub[l], slv = lvb[l];
  for (int k=0;k<896;++k){
    float p = pr[k];
    smu = fmaf(p, muW[k*2+l], smu);
    slv = fmaf(p, lvW[k*2+l], slv);
  }
  out_mu[t] = smu; out_lv[t] = slv;
  float zv = fmaf(eps[t], __expf(0.5f*slv), smu);
  out_z[t] = zv; zws[t] = zv;
}

__global__ void compute_f_kernel(const float* __restrict__ zws, const float* __restrict__ decW,
                                 const float* __restrict__ decb, const float* __restrict__ pooled,
                                 float* __restrict__ f){
  int b = blockIdx.x;
  float z0 = zws[b*2], z1 = zws[b*2+1];
  for (int k = threadIdx.x; k < 896; k += 256){
    float zd = fmaf(z0, decW[k], fmaf(z1, decW[896+k], decb[k]));
    f[b*896+k] = zd / pooled[b*896+k];
  }
}

__global__ void dec_atom_kernel(ushort_t* __restrict__ a, const float* __restrict__ f){
  int e = blockIdx.x*256+threadIdx.x; // n*128
  int c = e & 127; int b = e >> 14;
  a[e] = f2bf(softplusf_(bf2f(a[e]) * f[b*896 + c]));
}

__global__ void dec_bond_kernel(ushort_t* __restrict__ nb, const float* __restrict__ f){
  int i = blockIdx.x; int off = blockIdx.y*256 + threadIdx.x; // off < 768
  int b = i >> 7;
  size_t e = (size_t)i*768 + off;
  nb[e] = f2bf(softplusf_(bf2f(nb[e]) * f[b*896 + 128 + off]));
}

// ---------------- final embeddings ----------------
__global__ void embed_atom2_kernel(const ushort_t* __restrict__ a, const float* __restrict__ W,
                                   const float* __restrict__ bias, float* __restrict__ za2){
  __shared__ float row[128];
  int i = blockIdx.x; int t = threadIdx.x; // 128
  row[t] = bf2f(a[(size_t)i*128+t]);
  __syncthreads();
  if (t < 92){
    float s = bias[t];
#pragma unroll
    for (int k=0;k<128;++k) s = fmaf(row[k], W[k*92+t], s);
    za2[(size_t)i*92+t] = sigmoidf_(s);
  }
}

__global__ void bproj_kernel(const ushort_t* __restrict__ nb, const float* __restrict__ W,
                             const float* __restrict__ bias, float* __restrict__ bp){
  __shared__ float Ws[64][41];
  __shared__ float rows[6][64];
  int t = threadIdx.x; // 256
  for (int e=t; e<64*41; e+=256) Ws[e/41][e%41] = W[e];
  int r0 = blockIdx.x*6;
  for (int e=t; e<6*64; e+=256){
    int rr = e>>6, c = e&63;
    rows[rr][c] = bf2f(nb[(size_t)(r0+rr)*64 + c]);
  }
  __syncthreads();
  if (t < 246){
    int rr = t/41, o = t - rr*41;
    float s = bias[o];
#pragma unroll
    for (int k=0;k<64;++k) s = fmaf(rows[rr][k], Ws[k][o], s);
    bp[(size_t)(r0+rr)*41 + o] = sigmoidf_(s);
  }
}

__global__ void zdec_v2(const float* __restrict__ za2, const float* __restrict__ bp,
                        const int* __restrict__ idx, float* __restrict__ out){
  int e0 = blockIdx.x*2048 + threadIdx.x;
#pragma unroll
  for (int i=0;i<8;++i){
    int e = e0 + i*256;
    int r = e/225, c = e - r*225;
    float v;
    if (c < 92)       v = za2[(size_t)(r/12)*92 + c];
    else if (c < 184) v = za2[(size_t)idx[r]*92 + (c-92)];
    else              v = bp[(size_t)r*41 + (c-184)];
    __builtin_nontemporal_store(v, out + (size_t)e);
  }
}

// ---------------- host side ----------------
struct WsPlan {
  ushort_t *Abf, *NBbf, *Wt;
  __half* big;
  float *asum, *pooled, *fbuf, *zws, *eps, *mean, *ssq;
  int* cnt;
  double *cs, *st;
};

static void conv_pass(const WsPlan& P, const int* idx,
                      const float* Wa, const float* Wb,
                      const float* g1a, const float* b1a, const float* g1b, const float* b1b,
                      const float* g2a, const float* b2a,
                      hipStream_t stream){
  wtr2_kernel<<<dim3(10,12), 256, 0, stream>>>(Wa, Wb, P.Wt, (float*)P.cs);
  colsum_all<<<512, 256, 0, stream>>>(P.Abf, P.NBbf, P.cnt, P.cs);
  mean_kernel<<<6, 64, 0, stream>>>(P.cs, P.Wt, 384, P.mean);
  conv_gemm_v6<<<dim3(NM/128, 3), 256, 0, stream>>>(P.Abf, P.NBbf, idx, P.Wt, P.mean, P.big, P.ssq);
  const __half* O0 = P.big;
  const __half* O1 = P.big + (size_t)NM*128;
  const __half* O2 = P.big + (size_t)NM*256;
  apply_ga_v3<<<N_ATOM/16, 256, 0, stream>>>(O0, O1, P.ssq, g1a, b1a, P.asum);
  asum_stats<<<64, 256, 0, stream>>>(P.asum, P.st);
  apply_out1_v2<<<N_ATOM*128/256, 256, 0, stream>>>(P.Abf, P.asum, P.st, g2a, b2a);
  apply_gb_v3<<<NM/32, 256, 0, stream>>>(O2, P.NBbf, P.ssq, g1b, b1b);
}

extern "C" void kernel_launch(void* const* d_in, const int* in_sizes, int n_in,
                              void* d_out, int out_size, void* d_ws, size_t ws_size,
                              hipStream_t stream) {
  (void)in_sizes; (void)n_in; (void)out_size; (void)ws_size;
  const float* atom_fea   = (const float*)d_in[0];
  const float* nbr_fea    = (const float*)d_in[1];
  const int*   idx        = (const int*)d_in[2];
  const float* emb_atom_W = (const float*)d_in[4];
  const float* emb_atom_b = (const float*)d_in[5];
  const float* emb_bond_W = (const float*)d_in[6];
  const float* emb_bond_b = (const float*)d_in[7];
  const float* emb_atom2_W= (const float*)d_in[8];
  const float* emb_atom2_b= (const float*)d_in[9];
  const float* emb_bond2_W= (const float*)d_in[10];
  const float* emb_bond2_b= (const float*)d_in[11];
  const float* mu_W       = (const float*)d_in[12];
  const float* mu_b       = (const float*)d_in[13];
  const float* lv_W       = (const float*)d_in[14];
  const float* lv_b       = (const float*)d_in[15];
  const float* dec_W      = (const float*)d_in[16];
  const float* dec_b      = (const float*)d_in[17];
  const float* c1_Wa  = (const float*)d_in[18];
  const float* c1_Wb  = (const float*)d_in[19];
  const float* c1_g1a = (const float*)d_in[20];
  const float* c1_b1a = (const float*)d_in[21];
  const float* c1_g1b = (const float*)d_in[22];
  const float* c1_b1b = (const float*)d_in[23];
  const float* c1_g2a = (const float*)d_in[24];
  const float* c1_b2a = (const float*)d_in[25];
  const float* c2_Wa  = (const float*)d_in[26];
  const float* c2_Wb  = (const float*)d_in[27];
  const float* c2_g1a = (const float*)d_in[28];
  const float* c2_b1a = (const float*)d_in[29];
  const float* c2_g1b = (const float*)d_in[30];
  const float* c2_b1b = (const float*)d_in[31];
  const float* c2_g2a = (const float*)d_in[32];
  const float* c2_b2a = (const float*)d_in[33];

  float* out = (float*)d_out;

  WsPlan P;
  char* w = (char*)d_ws;
  auto alloc = [&](size_t bytes) -> char* {
    char* p = w; w += (bytes + 255) & ~(size_t)255; return p;
  };
  P.Abf    = (ushort_t*)alloc((size_t)N_ATOM*128*2);
  P.NBbf   = (ushort_t*)alloc((size_t)NM*64*2);
  P.big    = (__half*)  alloc((size_t)NM*384*2);
  P.asum   = (float*)   alloc((size_t)N_ATOM*128*4);
  P.pooled = (float*)   alloc(114688*4);
  P.fbuf   = (float*)   alloc(114688*4);
  P.Wt     = (ushort_t*)alloc(384*320*2);
  P.zws    = (float*)   alloc(256*4);
  P.eps    = (float*)   alloc(256*4);
  P.mean   = (float*)   alloc(384*4);
  P.cnt    = (int*)     alloc(N_ATOM*4);
  P.cs     = (double*)  alloc(320*8);   // cs, st, ssq contiguous (zeroed in wtr2)
  P.st     = (double*)  alloc(256*8);
  P.ssq    = (float*)   alloc(384*4);
  float* za2   = P.asum;                 // reuse after conv stacks
  float* bproj = (float*)P.big;          // reuse big in the final phase

  gen_eps_kernel<<<1, 256, 0, stream>>>(P.eps);
  tif_v2<<<21600, 256, 0, stream>>>(atom_fea, nbr_fea, idx, out + O_TIF);
  embed_atom_kernel<<<N_ATOM, 128, 0, stream>>>(atom_fea, emb_atom_W, emb_atom_b, P.Abf);
  embed_bond_kernel<<<NM/4, 256, 0, stream>>>(nbr_fea, emb_bond_W, emb_bond_b, P.NBbf);
  hipMemsetAsync(P.cnt, 0, N_ATOM*sizeof(int), stream);
  cnt_kernel<<<NM/256, 256, 0, stream>>>(idx, P.cnt);

  for (int L=0; L<3; ++L){
    conv_pass(P, idx, c1_Wa + (size_t)L*320*256, c1_Wb + (size_t)L*320*128,
              c1_g1a+L*256, c1_b1a+L*256, c1_g1b+L*128, c1_b1b+L*128,
              c1_g2a+L*128, c1_b2a+L*128, stream);
  }

  pool_a_kernel<<<NCRY, 128, 0, stream>>>(P.Abf, P.pooled);
  pool_n_kernel<<<NCRY, 768, 0, stream>>>(P.NBbf, P.pooled);
  muz_kernel<<<1, 256, 0, stream>>>(P.pooled, mu_W, mu_b, lv_W, lv_b, P.eps,
                                    out + O_MU, out + O_LV, out + O_Z, P.zws);
  compute_f_kernel<<<NCRY, 256, 0, stream>>>(P.zws, dec_W, dec_b, P.pooled, P.fbuf);
  dec_atom_kernel<<<N_ATOM*128/256, 256, 0, stream>>>(P.Abf, P.fbuf);
  dim3 gdb(N_ATOM, 3);
  dec_bond_kernel<<<gdb, 256, 0, stream>>>(P.NBbf, P.fbuf);

  for (int L=0; L<3; ++L){
    conv_pass(P, idx, c2_Wa + (size_t)L*320*256, c2_Wb + (size_t)L*320*128,
              c2_g1a+L*256, c2_b1a+L*256, c2_g1b+L*128, c2_b1b+L*128,
              c2_g2a+L*128, c2_b2a+L*128, stream);
  }

  embed_atom2_kernel<<<N_ATOM, 128, 0, stream>>>(P.Abf, emb_atom2_W, emb_atom2_b, za2);
  bproj_kernel<<<NM/6, 256, 0, stream>>>(P.NBbf, emb_bond2_W, emb_bond2_b, bproj);
  zdec_v2<<<21600, 256, 0, stream>>>(za2, bproj, idx, out + O_ZDEC);
}

// Round 9
// 2615.484 us; speedup vs baseline: 1.3025x; 1.2371x over previous
//
#include <hip/hip_runtime.h>
#include <hip/hip_bf16.h>
#include <hip/hip_fp16.h>
#include <cstdint>
#include <cstddef>

// ---------------- constants ----------------
#define N_ATOM 16384
#define M_NBR  12
#define NCRY   128
#define NM     (N_ATOM*M_NBR) // 196608

// output offsets (floats)
#define O_ZDEC 0
#define O_MU   44236800
#define O_LV   44237056
#define O_Z    44237312
#define O_TIF  44237568

typedef unsigned short ushort_t;
typedef float f32x4 __attribute__((ext_vector_type(4)));
typedef short bf16x8 __attribute__((ext_vector_type(8)));
typedef unsigned int u32x4 __attribute__((ext_vector_type(4)));

__device__ __forceinline__ float sigmoidf_(float x){ return 1.f/(1.f+__expf(-x)); }
__device__ __forceinline__ float softplusf_(float x){ return fmaxf(x,0.f) + log1pf(__expf(-fabsf(x))); }
__device__ __forceinline__ uint32_t rotl32_(uint32_t x, int r){ return (x<<r)|(x>>(32-r)); }
__device__ __forceinline__ float bf2f(ushort_t u){ return __uint_as_float(((uint32_t)u)<<16); }
__device__ __forceinline__ ushort_t f2bf(float x){
  uint32_t u = __float_as_uint(x);
  uint32_t r = (u + 0x7FFFu + ((u>>16)&1u)) >> 16;
  return (ushort_t)r;
}

// async global->LDS, 16B per lane; LDS dest = wave-uniform base + lane*16
#define GLDS16(g, l) __builtin_amdgcn_global_load_lds( \
    (const __attribute__((address_space(1))) void*)(g), \
    (__attribute__((address_space(3))) void*)(l), 16, 0, 0)

// ---------------- eps = jax.random.normal(key(42), (128,2)) ----------------
__global__ void gen_eps_kernel(float* __restrict__ eps){
  int j = threadIdx.x; // 256
  const uint32_t k0 = 0u, k1 = 42u;
  const uint32_t ks2 = k0 ^ k1 ^ 0x1BD11BDAu;
  uint32_t x0 = 0u + k0;
  uint32_t x1 = (uint32_t)j + k1;
#define RND_(r) { x0 += x1; x1 = rotl32_(x1, r); x1 ^= x0; }
  RND_(13) RND_(15) RND_(26) RND_(6)  x0 += k1;  x1 += ks2 + 1u;
  RND_(17) RND_(29) RND_(16) RND_(24) x0 += ks2; x1 += k0 + 2u;
  RND_(13) RND_(15) RND_(26) RND_(6)  x0 += k0;  x1 += k1 + 3u;
  RND_(17) RND_(29) RND_(16) RND_(24) x0 += k1;  x1 += ks2 + 4u;
  RND_(13) RND_(15) RND_(26) RND_(6)  x0 += ks2; x1 += k0 + 5u;
#undef RND_
  uint32_t bits = x0 ^ x1;
  float f = __uint_as_float((bits >> 9) | 0x3f800000u) - 1.0f;
  float u = __fadd_rn(__fmul_rn(f, 1.99999994f), -0.99999994f);
  u = fmaxf(-0.99999994f, u);
  float w = -log1pf(-u*u);
  float p;
  if (w < 5.0f){
    w -= 2.5f;
    p = 2.81022636e-08f;
    p = fmaf(p, w, 3.43273939e-07f);
    p = fmaf(p, w, -3.5233877e-06f);
    p = fmaf(p, w, -4.39150654e-06f);
    p = fmaf(p, w, 0.00021858087f);
    p = fmaf(p, w, -0.00125372503f);
    p = fmaf(p, w, -0.00417768164f);
    p = fmaf(p, w, 0.246640727f);
    p = fmaf(p, w, 1.50140941f);
  } else {
    w = sqrtf(w) - 3.0f;
    p = -0.000200214257f;
    p = fmaf(p, w, 0.000100950558f);
    p = fmaf(p, w, 0.00134934322f);
    p = fmaf(p, w, -0.00367342844f);
    p = fmaf(p, w, 0.00573950773f);
    p = fmaf(p, w, -0.0076224613f);
    p = fmaf(p, w, 0.00943887047f);
    p = fmaf(p, w, 1.00167406f);
    p = fmaf(p, w, 2.83297682f);
  }
  eps[j] = 1.41421356237f * (p * u);
}

// ---------------- total_input_fea output (coalesced, NT stores) ------
__global__ void tif_v2(const float* __restrict__ atom, const float* __restrict__ nbr,
                       const int* __restrict__ idx, float* __restrict__ out){
  int e0 = blockIdx.x*2048 + threadIdx.x;
#pragma unroll
  for (int i=0;i<8;++i){
    int e = e0 + i*256;
    int r = e/225, c = e - r*225;
    float v;
    if (c < 92)       v = atom[(r/12)*92 + c];
    else if (c < 184) v = atom[idx[r]*92 + (c-92)];
    else              v = nbr[(size_t)r*41 + (c-184)];
    __builtin_nontemporal_store(v, out + (size_t)e);
  }
}

// ---------------- embeddings (write bf16 masters) ----------------
__global__ void embed_atom_kernel(const float* __restrict__ atom, const float* __restrict__ W,
                                  const float* __restrict__ bias, ushort_t* __restrict__ a0){
  __shared__ float row[92];
  int i = blockIdx.x; int t = threadIdx.x; // 128
  if (t < 92) row[t] = atom[i*92+t];
  __syncthreads();
  float s = bias[t];
#pragma unroll
  for (int k=0;k<92;++k) s = fmaf(row[k], W[k*128+t], s);
  a0[(size_t)i*128+t] = f2bf(s);
}

__global__ void embed_bond_kernel(const float* __restrict__ nbr, const float* __restrict__ W,
                                  const float* __restrict__ bias, ushort_t* __restrict__ nb0){
  __shared__ float rows[4][41];
  int r0 = blockIdx.x*4; int t = threadIdx.x; // 256
  if (t < 164) rows[t/41][t%41] = nbr[(size_t)r0*41 + t];
  __syncthreads();
  int rr = t >> 6, c = t & 63;
  float s = bias[c];
#pragma unroll
  for (int k=0;k<41;++k) s = fmaf(rows[rr][k], W[k*64+c], s);
  nb0[(size_t)(r0+rr)*64 + c] = f2bf(s);
}

// ---------------- weight transpose (Wa+Wb fused) + stats zeroing ----------
// also zeroes sums(768 f32) + st(256 f32) = 1024 floats
__global__ void wtr2_kernel(const float* __restrict__ Wa, const float* __restrict__ Wb,
                            ushort_t* __restrict__ Wt, float* __restrict__ zstats){
  __shared__ ushort_t tile[32][33];
  if (blockIdx.x == 0 && blockIdx.y == 0){
#pragma unroll
    for (int k=0;k<4;++k) zstats[threadIdx.x + k*256] = 0.f;
  }
  int by = blockIdx.y;
  const float* W; int NO, o0, obase;
  if (by < 8){ W = Wa; NO = 256; o0 = by*32; obase = o0; }
  else       { W = Wb; NO = 128; o0 = (by-8)*32; obase = 256 + o0; }
  int k0 = blockIdx.x*32;
  int tx = threadIdx.x & 31, ty = threadIdx.x >> 5; // 256 thr
#pragma unroll
  for (int i = ty; i < 32; i += 8)
    tile[i][tx] = f2bf(W[(size_t)(k0+i)*NO + o0 + tx]);
  __syncthreads();
#pragma unroll
  for (int i = ty; i < 32; i += 8)
    Wt[(size_t)(obase+i)*320 + k0 + tx] = tile[tx][i];
}

// ---------------- MFMA conv GEMM v7 ----------------
// BM=256 x BN=128 per block, 4 waves (each 64 rows x 128 cols, acc 4x8 f32x4).
// BK=32 double-buffered via global_load_lds. Output col-block-major [3][NM][128],
// contiguous NT stores. Epilogue accumulates per-col sum+ssq (f32 atomics).
__launch_bounds__(256, 2)
__global__ void conv_gemm_v7(const ushort_t* __restrict__ a_bf, const ushort_t* __restrict__ nb_bf,
                             const int* __restrict__ idx, const ushort_t* __restrict__ Wt,
                             __half* __restrict__ O, float* __restrict__ sums){
  __shared__ ushort_t sm[34816];   // staging: As 2x8192 @0, Bs 2x4096 @16384; epilogue [256][136]
  __shared__ float sqred[256];     // 128 sum + 128 ssq (this col block)
  __shared__ int idxs[256];
  ushort_t* As = sm;
  ushort_t* Bs = sm + 16384;
  const int t = threadIdx.x;
  const int lane = t & 63;
  const int w = t >> 6;
  const int lm = lane & 15, lg = lane >> 4;
  const int row0 = blockIdx.x * 256;
  const int cb   = blockIdx.y;          // col-block 0..2
  const int col0 = cb * 128;
  __half* Ob = O + (size_t)cb * ((size_t)NM*128);

  idxs[t] = idx[row0 + t];
  sqred[t] = 0.f;

  auto stage = [&](int ks, int b_){
    ushort_t* Ad = As + b_*8192;
    ushort_t* Bd = Bs + b_*4096;
#pragma unroll
    for (int i=0;i<4;++i){
      int e = t + i*256;              // 0..1023
      int r = e >> 2, ch = e & 3;
      const ushort_t* ga;
      if (ks < 4)      ga = a_bf + (size_t)((row0+r)/12)*128 + ks*32 + ch*8;
      else if (ks < 8) ga = a_bf + (size_t)idxs[r]*128 + (ks-4)*32 + ch*8;
      else             ga = nb_bf + (size_t)(row0+r)*64 + (ks-8)*32 + ch*8;
      GLDS16(ga, Ad + e*8);
    }
#pragma unroll
    for (int i=0;i<2;++i){
      int e = t + i*256;              // 0..511
      int r = e >> 2, ch = e & 3;
      GLDS16(Wt + (size_t)(col0+r)*320 + ks*32 + ch*8, Bd + e*8);
    }
  };

  stage(0, 0);
  __syncthreads();   // drains vmcnt (buf0 ready) + makes idxs visible

  f32x4 acc[4][8] = {};
  int buf = 0;
#pragma unroll
  for (int ks = 0; ks < 10; ++ks){
    if (ks < 9) stage(ks+1, buf^1);
    const ushort_t* Ab = As + buf*8192;
    const ushort_t* Bb = Bs + buf*4096;
    bf16x8 afr[4], bfr[8];
#pragma unroll
    for (int fm=0; fm<4; ++fm)
      afr[fm] = *(const bf16x8*)&Ab[(w*64 + fm*16 + lm)*32 + lg*8];
#pragma unroll
    for (int fn=0; fn<8; ++fn)
      bfr[fn] = *(const bf16x8*)&Bb[(fn*16 + lm)*32 + lg*8];
#pragma unroll
    for (int fm=0; fm<4; ++fm)
#pragma unroll
      for (int fn=0; fn<8; ++fn)
        acc[fm][fn] = __builtin_amdgcn_mfma_f32_16x16x32_bf16(afr[fm], bfr[fn], acc[fm][fn], 0, 0, 0);
    __syncthreads();
    buf ^= 1;
  }

  // epilogue: stage f16 tile [256][136] in LDS (raw, uncentered), then coalesced
  // NT stores + fused per-col sum/ssq
#pragma unroll
  for (int fm=0; fm<4; ++fm){
    int rw = w*64 + fm*16 + lg*4;
#pragma unroll
    for (int fn=0; fn<8; ++fn){
      int cl = fn*16 + lm;
#pragma unroll
      for (int j=0; j<4; ++j){
        __half h = __float2half(acc[fm][fn][j]);
        sm[(rw+j)*136 + cl] = *(ushort_t*)&h;
      }
    }
  }
  __syncthreads();

  const int cch = t & 15, rb = t >> 4;
  float s1[8] = {0.f,0.f,0.f,0.f,0.f,0.f,0.f,0.f};
  float s2[8] = {0.f,0.f,0.f,0.f,0.f,0.f,0.f,0.f};
#pragma unroll
  for (int i=0; i<16; ++i){
    int row = rb + i*16;
    u32x4 v = *(const u32x4*)&sm[row*136 + cch*8];
    __builtin_nontemporal_store(v, (u32x4*)(Ob + (size_t)(row0+row)*128 + cch*8));
    const __half* hp = (const __half*)&v;
#pragma unroll
    for (int k=0;k<8;++k){
      float f = __half2float(hp[k]);
      s1[k] += f;
      s2[k] += f*f;
    }
  }
#pragma unroll
  for (int k=0;k<8;++k){
    atomicAdd(&sqred[cch*8+k], s1[k]);
    atomicAdd(&sqred[128+cch*8+k], s2[k]);
  }
  __syncthreads();
  if (t < 128){
    atomicAdd(&sums[col0 + t], sqred[t]);          // sum
    atomicAdd(&sums[384 + col0 + t], sqred[128+t]);// ssq
  }
}

// ---------------- conv apply kernels (BN from sum/ssq; stats fused) ----
// ga lives in O0 (cols 0-127) and O1 (cols 128-255), each [NM][128]
__global__ void apply_ga_v4(const __half* __restrict__ O0, const __half* __restrict__ O1,
                            const float* __restrict__ sums,
                            const float* __restrict__ g1a, const float* __restrict__ b1a,
                            float* __restrict__ asum, float* __restrict__ st){
  __shared__ float red[256];
  int t = threadIdx.x;           // 256 = 16 atoms x 16 col-chunks
  red[t] = 0.f;
  int c8 = t & 15, al = t >> 4;
  int i = blockIdx.x*16 + al;
  int c0 = c8*8;
  float gf[8], bfv[8], gc[8], bcv[8];
#pragma unroll
  for (int k=0;k<8;++k){
    int c = c0+k;
    float mf = sums[c]*(1.f/NM);
    float rf = rsqrtf(sums[384+c]*(1.f/NM) - mf*mf + 1e-5f);
    gf[k]  = g1a[c]*rf;      bfv[k] = b1a[c] - mf*gf[k];
    float mc = sums[c+128]*(1.f/NM);
    float rc = rsqrtf(sums[384+c+128]*(1.f/NM) - mc*mc + 1e-5f);
    gc[k]  = g1a[c+128]*rc;  bcv[k] = b1a[c+128] - mc*gc[k];
  }
  float s[8] = {0.f,0.f,0.f,0.f,0.f,0.f,0.f,0.f};
  size_t base = (size_t)i*12*128;
#pragma unroll
  for (int j=0;j<12;++j){
    u32x4 vf = __builtin_nontemporal_load((const u32x4*)(O0 + base + j*128 + c0));
    u32x4 vc = __builtin_nontemporal_load((const u32x4*)(O1 + base + j*128 + c0));
    const __half* hf = (const __half*)&vf;
    const __half* hc = (const __half*)&vc;
#pragma unroll
    for (int k=0;k<8;++k)
      s[k] += sigmoidf_(fmaf(__half2float(hf[k]), gf[k], bfv[k]))
            * softplusf_(fmaf(__half2float(hc[k]), gc[k], bcv[k]));
  }
  float* dst = asum + (size_t)i*128 + c0;
  __syncthreads();               // red zero visible before cross-thread atomics
#pragma unroll
  for (int k=0;k<8;++k){
    dst[k] = s[k];
    atomicAdd(&red[c0+k], s[k]);
    atomicAdd(&red[128+c0+k], s[k]*s[k]);
  }
  __syncthreads();
  atomicAdd(&st[t], red[t]);     // st[0..127] sum, st[128..255] ssq
}

// apply_out1 with inline BN2 stats from st
__global__ void apply_out1_v3(ushort_t* __restrict__ a0, const float* __restrict__ asum,
                              const float* __restrict__ st, const float* __restrict__ g2a,
                              const float* __restrict__ b2a){
  int e = blockIdx.x*256 + threadIdx.x; // n*128
  int c = e & 127;
  float m  = st[c]*(1.f/N_ATOM);
  float var = st[128+c]*(1.f/N_ATOM) - m*m;
  float rs = rsqrtf(var + 1e-5f);
  float g = g2a[c]*rs;
  float b = b2a[c] - m*g;
  a0[e] = f2bf(softplusf_(bf2f(a0[e]) + fmaf(asum[e], g, b)));
}

// gb lives in O2, [NM][128] (filter 0-63 -> global col 256+c, core 64-127 -> 320+c)
__global__ void apply_gb_v4(const __half* __restrict__ O2, ushort_t* __restrict__ nb,
                            const float* __restrict__ sums, const float* __restrict__ g1b,
                            const float* __restrict__ b1b){
  int t = threadIdx.x;          // 256 = 32 rows x 8 col-chunks
  int c8 = t & 7, rloc = t >> 3;
  int r = blockIdx.x*32 + rloc;
  int c0 = c8*8;
  float gf[8], bfv[8], gc[8], bcv[8];
#pragma unroll
  for (int k=0;k<8;++k){
    int c = c0+k;
    float mf = sums[256+c]*(1.f/NM);
    float rf = rsqrtf(sums[384+256+c]*(1.f/NM) - mf*mf + 1e-5f);
    gf[k]  = g1b[c]*rf;      bfv[k] = b1b[c] - mf*gf[k];
    float mc = sums[256+64+c]*(1.f/NM);
    float rc = rsqrtf(sums[384+256+64+c]*(1.f/NM) - mc*mc + 1e-5f);
    gc[k]  = g1b[c+64]*rc;   bcv[k] = b1b[c+64] - mc*gc[k];
  }
  size_t gbase = (size_t)r*128;
  u32x4 vf = __builtin_nontemporal_load((const u32x4*)(O2 + gbase + c0));
  u32x4 vc = __builtin_nontemporal_load((const u32x4*)(O2 + gbase + 64 + c0));
  const __half* hf = (const __half*)&vf;
  const __half* hc = (const __half*)&vc;
  ushort_t* np = nb + (size_t)r*64 + c0;
  u32x4 old = *(const u32x4*)np;
  const ushort_t* op = (const ushort_t*)&old;
  u32x4 outv;
  ushort_t* ov = (ushort_t*)&outv;
#pragma unroll
  for (int k=0;k<8;++k){
    float x = bf2f(op[k]) + sigmoidf_(fmaf(__half2float(hf[k]), gf[k], bfv[k]))
                          * softplusf_(fmaf(__half2float(hc[k]), gc[k], bcv[k]));
    ov[k] = f2bf(softplusf_(x));
  }
  *(u32x4*)np = outv;
}

// ---------------- pooling / VAE / decode ----------------
__global__ void pool_a_kernel(const ushort_t* __restrict__ a, float* __restrict__ pooled){
  int b = blockIdx.x; int c = threadIdx.x; // 128
  float s = 0.f;
  for (int i=0;i<128;++i) s += bf2f(a[(size_t)((b<<7)+i)*128 + c]);
  pooled[b*896 + c] = softplusf_(s * (1.f/128.f));
}

__launch_bounds__(768)
__global__ void pool_n_kernel(const ushort_t* __restrict__ nb, float* __restrict__ pooled){
  int b = blockIdx.x; int t = threadIdx.x; // 768
  float s = 0.f;
  for (int i=0;i<128;++i) s += bf2f(nb[(size_t)((b<<7)+i)*768 + t]);
  pooled[b*896 + 128 + t] = softplusf_(s * (1.f/128.f));
}

__global__ void muz_kernel(const float* __restrict__ pooled, const float* __restrict__ muW,
                           const float* __restrict__ mub, const float* __restrict__ lvW,
                           const float* __restrict__ lvb, const float* __restrict__ eps,
                           float* __restrict__ out_mu, float* __restrict__ out_lv,
                           float* __restrict__ out_z, float* __restrict__ zws){
  int t = threadIdx.x; // 256 -> (b,l)
  int b = t >> 1, l = t & 1;
  const float* pr = pooled + b*896;
  float smu = mub[l], slv = lvb[l];
  for (int k=0;k<896;++k){
    float p = pr[k];
    smu = fmaf(p, muW[k*2+l], smu);
    slv = fmaf(p, lvW[k*2+l], slv);
  }
  out_mu[t] = smu; out_lv[t] = slv;
  float zv = fmaf(eps[t], __expf(0.5f*slv), smu);
  out_z[t] = zv; zws[t] = zv;
}

__global__ void compute_f_kernel(const float* __restrict__ zws, const float* __restrict__ decW,
                                 const float* __restrict__ decb, const float* __restrict__ pooled,
                                 float* __restrict__ f){
  int b = blockIdx.x;
  float z0 = zws[b*2], z1 = zws[b*2+1];
  for (int k = threadIdx.x; k < 896; k += 256){
    float zd = fmaf(z0, decW[k], fmaf(z1, decW[896+k], decb[k]));
    f[b*896+k] = zd / pooled[b*896+k];
  }
}

__global__ void dec_atom_kernel(ushort_t* __restrict__ a, const float* __restrict__ f){
  int e = blockIdx.x*256+threadIdx.x; // n*128
  int c = e & 127; int b = e >> 14;
  a[e] = f2bf(softplusf_(bf2f(a[e]) * f[b*896 + c]));
}

__global__ void dec_bond_kernel(ushort_t* __restrict__ nb, const float* __restrict__ f){
  int i = blockIdx.x; int off = blockIdx.y*256 + threadIdx.x; // off < 768
  int b = i >> 7;
  size_t e = (size_t)i*768 + off;
  nb[e] = f2bf(softplusf_(bf2f(nb[e]) * f[b*896 + 128 + off]));
}

// ---------------- final embeddings ----------------
__global__ void embed_atom2_kernel(const ushort_t* __restrict__ a, const float* __restrict__ W,
                                   const float* __restrict__ bias, float* __restrict__ za2){
  __shared__ float row[128];
  int i = blockIdx.x; int t = threadIdx.x; // 128
  row[t] = bf2f(a[(size_t)i*128+t]);
  __syncthreads();
  if (t < 92){
    float s = bias[t];
#pragma unroll
    for (int k=0;k<128;++k) s = fmaf(row[k], W[k*92+t], s);
    za2[(size_t)i*92+t] = sigmoidf_(s);
  }
}

__global__ void bproj_kernel(const ushort_t* __restrict__ nb, const float* __restrict__ W,
                             const float* __restrict__ bias, float* __restrict__ bp){
  __shared__ float Ws[64][41];
  __shared__ float rows[6][64];
  int t = threadIdx.x; // 256
  for (int e=t; e<64*41; e+=256) Ws[e/41][e%41] = W[e];
  int r0 = blockIdx.x*6;
  for (int e=t; e<6*64; e+=256){
    int rr = e>>6, c = e&63;
    rows[rr][c] = bf2f(nb[(size_t)(r0+rr)*64 + c]);
  }
  __syncthreads();
  if (t < 246){
    int rr = t/41, o = t - rr*41;
    float s = bias[o];
#pragma unroll
    for (int k=0;k<64;++k) s = fmaf(rows[rr][k], Ws[k][o], s);
    bp[(size_t)(r0+rr)*41 + o] = sigmoidf_(s);
  }
}

__global__ void zdec_v2(const float* __restrict__ za2, const float* __restrict__ bp,
                        const int* __restrict__ idx, float* __restrict__ out){
  int e0 = blockIdx.x*2048 + threadIdx.x;
#pragma unroll
  for (int i=0;i<8;++i){
    int e = e0 + i*256;
    int r = e/225, c = e - r*225;
    float v;
    if (c < 92)       v = za2[(size_t)(r/12)*92 + c];
    else if (c < 184) v = za2[(size_t)idx[r]*92 + (c-92)];
    else              v = bp[(size_t)r*41 + (c-184)];
    __builtin_nontemporal_store(v, out + (size_t)e);
  }
}

// ---------------- host side ----------------
struct WsPlan {
  ushort_t *Abf, *NBbf, *Wt;
  __half* big;
  float *asum, *pooled, *fbuf, *zws, *eps, *sums, *st;
};

static void conv_pass(const WsPlan& P, const int* idx,
                      const float* Wa, const float* Wb,
                      const float* g1a, const float* b1a, const float* g1b, const float* b1b,
                      const float* g2a, const float* b2a,
                      hipStream_t stream){
  wtr2_kernel<<<dim3(10,12), 256, 0, stream>>>(Wa, Wb, P.Wt, P.sums);
  conv_gemm_v7<<<dim3(NM/256, 3), 256, 0, stream>>>(P.Abf, P.NBbf, idx, P.Wt, P.big, P.sums);
  const __half* O0 = P.big;
  const __half* O1 = P.big + (size_t)NM*128;
  const __half* O2 = P.big + (size_t)NM*256;
  apply_ga_v4<<<N_ATOM/16, 256, 0, stream>>>(O0, O1, P.sums, g1a, b1a, P.asum, P.st);
  apply_out1_v3<<<N_ATOM*128/256, 256, 0, stream>>>(P.Abf, P.asum, P.st, g2a, b2a);
  apply_gb_v4<<<NM/32, 256, 0, stream>>>(O2, P.NBbf, P.sums, g1b, b1b);
}

extern "C" void kernel_launch(void* const* d_in, const int* in_sizes, int n_in,
                              void* d_out, int out_size, void* d_ws, size_t ws_size,
                              hipStream_t stream) {
  (void)in_sizes; (void)n_in; (void)out_size; (void)ws_size;
  const float* atom_fea   = (const float*)d_in[0];
  const float* nbr_fea    = (const float*)d_in[1];
  const int*   idx        = (const int*)d_in[2];
  const float* emb_atom_W = (const float*)d_in[4];
  const float* emb_atom_b = (const float*)d_in[5];
  const float* emb_bond_W = (const float*)d_in[6];
  const float* emb_bond_b = (const float*)d_in[7];
  const float* emb_atom2_W= (const float*)d_in[8];
  const float* emb_atom2_b= (const float*)d_in[9];
  const float* emb_bond2_W= (const float*)d_in[10];
  const float* emb_bond2_b= (const float*)d_in[11];
  const float* mu_W       = (const float*)d_in[12];
  const float* mu_b       = (const float*)d_in[13];
  const float* lv_W       = (const float*)d_in[14];
  const float* lv_b       = (const float*)d_in[15];
  const float* dec_W      = (const float*)d_in[16];
  const float* dec_b      = (const float*)d_in[17];
  const float* c1_Wa  = (const float*)d_in[18];
  const float* c1_Wb  = (const float*)d_in[19];
  const float* c1_g1a = (const float*)d_in[20];
  const float* c1_b1a = (const float*)d_in[21];
  const float* c1_g1b = (const float*)d_in[22];
  const float* c1_b1b = (const float*)d_in[23];
  const float* c1_g2a = (const float*)d_in[24];
  const float* c1_b2a = (const float*)d_in[25];
  const float* c2_Wa  = (const float*)d_in[26];
  const float* c2_Wb  = (const float*)d_in[27];
  const float* c2_g1a = (const float*)d_in[28];
  const float* c2_b1a = (const float*)d_in[29];
  const float* c2_g1b = (const float*)d_in[30];
  const float* c2_b1b = (const float*)d_in[31];
  const float* c2_g2a = (const float*)d_in[32];
  const float* c2_b2a = (const float*)d_in[33];

  float* out = (float*)d_out;

  WsPlan P;
  char* w = (char*)d_ws;
  auto alloc = [&](size_t bytes) -> char* {
    char* p = w; w += (bytes + 255) & ~(size_t)255; return p;
  };
  P.Abf    = (ushort_t*)alloc((size_t)N_ATOM*128*2);
  P.NBbf   = (ushort_t*)alloc((size_t)NM*64*2);
  P.big    = (__half*)  alloc((size_t)NM*384*2);
  P.asum   = (float*)   alloc((size_t)N_ATOM*128*4);
  P.pooled = (float*)   alloc(114688*4);
  P.fbuf   = (float*)   alloc(114688*4);
  P.Wt     = (ushort_t*)alloc(384*320*2);
  P.zws    = (float*)   alloc(256*4);
  P.eps    = (float*)   alloc(256*4);
  P.sums   = (float*)   alloc(1024*4);   // sums[768] + st[256] contiguous (zeroed in wtr2)
  P.st     = P.sums + 768;
  float* za2   = P.asum;                 // reuse after conv stacks
  float* bproj = (float*)P.big;          // reuse big in the final phase

  gen_eps_kernel<<<1, 256, 0, stream>>>(P.eps);
  tif_v2<<<21600, 256, 0, stream>>>(atom_fea, nbr_fea, idx, out + O_TIF);
  embed_atom_kernel<<<N_ATOM, 128, 0, stream>>>(atom_fea, emb_atom_W, emb_atom_b, P.Abf);
  embed_bond_kernel<<<NM/4, 256, 0, stream>>>(nbr_fea, emb_bond_W, emb_bond_b, P.NBbf);

  for (int L=0; L<3; ++L){
    conv_pass(P, idx, c1_Wa + (size_t)L*320*256, c1_Wb + (size_t)L*320*128,
              c1_g1a+L*256, c1_b1a+L*256, c1_g1b+L*128, c1_b1b+L*128,
              c1_g2a+L*128, c1_b2a+L*128, stream);
  }

  pool_a_kernel<<<NCRY, 128, 0, stream>>>(P.Abf, P.pooled);
  pool_n_kernel<<<NCRY, 768, 0, stream>>>(P.NBbf, P.pooled);
  muz_kernel<<<1, 256, 0, stream>>>(P.pooled, mu_W, mu_b, lv_W, lv_b, P.eps,
                                    out + O_MU, out + O_LV, out + O_Z, P.zws);
  compute_f_kernel<<<NCRY, 256, 0, stream>>>(P.zws, dec_W, dec_b, P.pooled, P.fbuf);
  dec_atom_kernel<<<N_ATOM*128/256, 256, 0, stream>>>(P.Abf, P.fbuf);
  dim3 gdb(N_ATOM, 3);
  dec_bond_kernel<<<gdb, 256, 0, stream>>>(P.NBbf, P.fbuf);

  for (int L=0; L<3; ++L){
    conv_pass(P, idx, c2_Wa + (size_t)L*320*256, c2_Wb + (size_t)L*320*128,
              c2_g1a+L*256, c2_b1a+L*256, c2_g1b+L*128, c2_b1b+L*128,
              c2_g2a+L*128, c2_b2a+L*128, stream);
  }

  embed_atom2_kernel<<<N_ATOM, 128, 0, stream>>>(P.Abf, emb_atom2_W, emb_atom2_b, za2);
  bproj_kernel<<<NM/6, 256, 0, stream>>>(P.NBbf, emb_bond2_W, emb_bond2_b, bproj);
  zdec_v2<<<21600, 256, 0, stream>>>(za2, bproj, idx, out + O_ZDEC);
}